// Round 5
// baseline (438.622 us; speedup 1.0000x reference)
//
#include <hip/hip_runtime.h>
#include <math.h>

#define DIMC 256
#define NTOK 1024   // H*W
#define QKVN 768
#define HDIM 32
#define SPLITS 2    // KV split factor (po = 4 MF; keeps ws peak < 53 MB proven-safe)

__device__ __forceinline__ float gelu_f(float y) {
  return 0.5f * y * (1.f + erff(y * 0.70710678118654752f));
}

// ---------------- depthwise 3x3, NCHW -> NCHW ----------------
__global__ void dwconv_k(const float* __restrict__ x, const float* __restrict__ w,
                         const float* __restrict__ b, float* __restrict__ y) {
  int bc = blockIdx.x;              // b*256 + c, 0..2047
  int c = bc & (DIMC - 1);
  float wr[9];
#pragma unroll
  for (int i = 0; i < 9; i++) wr[i] = w[c * 9 + i];
  float bb = b[c];
  const float* xp = x + (size_t)bc * NTOK;
  float* yp = y + (size_t)bc * NTOK;
  for (int p = threadIdx.x; p < NTOK; p += 256) {
    int hh = p >> 5, ww = p & 31;
    float acc = bb;
#pragma unroll
    for (int dh = 0; dh < 3; dh++) {
      int h2 = hh + dh - 1;
      if ((unsigned)h2 < 32u) {
#pragma unroll
        for (int dw = 0; dw < 3; dw++) {
          int w2 = ww + dw - 1;
          if ((unsigned)w2 < 32u) acc += xp[h2 * 32 + w2] * wr[dh * 3 + dw];
        }
      }
    }
    yp[p] = acc;
  }
}

// ---------------- tiled fp32 GEMM: C[M,N] = A[M,K=256] * W[N,K=256]^T (+bias) ----
// AT=true: A stored as [B][C][HW] (k-major); tile rows read contiguously along HW.
template <int BM, int BN, int TM, int TN, bool AT, bool BIAS>
__global__ __launch_bounds__(256) void gemm_k(const float* __restrict__ A,
                                              const float* __restrict__ W,
                                              const float* __restrict__ bias,
                                              float* __restrict__ C, int N) {
  constexpr int KB = 16;
  __shared__ float As[KB][BM];
  __shared__ float Bs[KB][BN];
  static_assert((BM / TM) * (BN / TN) == 256, "thread grid");
  const int t = threadIdx.x;
  const int m0 = blockIdx.y * BM;
  const int n0 = blockIdx.x * BN;
  constexpr int NTC = BN / TN;
  const int tr = (t / NTC) * TM;
  const int tc = (t % NTC) * TN;
  float acc[TM][TN] = {};
  for (int k0 = 0; k0 < 256; k0 += KB) {
    __syncthreads();
    if (AT) {
      constexpr int RPK = BM / 4;              // float4 per k-row
      constexpr int LD = (KB * RPK) / 256;
      int b = m0 >> 10;
      int hw0 = m0 & 1023;
#pragma unroll
      for (int u = 0; u < LD; u++) {
        int f = t + u * 256;
        int k = f / RPK;
        int r4 = (f % RPK) * 4;
        float4 v = *(const float4*)(A + ((size_t)(b * 256 + k0 + k) << 10) + hw0 + r4);
        *(float4*)&As[k][r4] = v;
      }
    } else {
      constexpr int LD = (BM * KB / 4) / 256;
#pragma unroll
      for (int u = 0; u < LD; u++) {
        int f = t + u * 256;
        int r = f >> 2;
        int k4 = (f & 3) << 2;
        float4 v = *(const float4*)(A + (size_t)(m0 + r) * 256 + k0 + k4);
        As[k4 + 0][r] = v.x; As[k4 + 1][r] = v.y;
        As[k4 + 2][r] = v.z; As[k4 + 3][r] = v.w;
      }
    }
    {
      constexpr int LD = (BN * KB / 4) / 256;
#pragma unroll
      for (int u = 0; u < LD; u++) {
        int f = t + u * 256;
        int o = f >> 2;
        int k4 = (f & 3) << 2;
        float4 v = *(const float4*)(W + (size_t)(n0 + o) * 256 + k0 + k4);
        Bs[k4 + 0][o] = v.x; Bs[k4 + 1][o] = v.y;
        Bs[k4 + 2][o] = v.z; Bs[k4 + 3][o] = v.w;
      }
    }
    __syncthreads();
#pragma unroll
    for (int kk = 0; kk < KB; kk++) {
      float a[TM], bv[TN];
#pragma unroll
      for (int i = 0; i < TM; i += 4) *(float4*)&a[i] = *(const float4*)&As[kk][tr + i];
#pragma unroll
      for (int j = 0; j < TN; j += 4) *(float4*)&bv[j] = *(const float4*)&Bs[kk][tc + j];
#pragma unroll
      for (int i = 0; i < TM; i++)
#pragma unroll
        for (int j = 0; j < TN; j++) acc[i][j] += a[i] * bv[j];
    }
  }
#pragma unroll
  for (int i = 0; i < TM; i++) {
#pragma unroll
    for (int j = 0; j < TN; j += 4) {
      float4 v = {acc[i][j], acc[i][j + 1], acc[i][j + 2], acc[i][j + 3]};
      if (BIAS) {
        v.x += bias[n0 + tc + j + 0]; v.y += bias[n0 + tc + j + 1];
        v.z += bias[n0 + tc + j + 2]; v.w += bias[n0 + tc + j + 3];
      }
      *(float4*)(C + (size_t)(m0 + tr + i) * N + n0 + tc + j) = v;
    }
  }
}

// ---------------- l2-normalize k (cols 256..511 of qkv) --------------------------
__global__ void l2k_k(float* __restrict__ qkv) {
  int gq = blockIdx.x * 256 + threadIdx.x;   // quad id
  int n = gq >> 6;
  int q4 = gq & 63;
  float* p = qkv + (size_t)n * QKVN + 256 + (q4 << 2);
  float4 v = *(const float4*)p;
  float s = v.x * v.x + v.y * v.y + v.z * v.z + v.w * v.w;
#pragma unroll
  for (int m = 1; m < 8; m <<= 1) s += __shfl_xor(s, m, 64);
  float inv = 1.f / fmaxf(sqrtf(s), 1e-12f);
  v.x *= inv; v.y *= inv; v.z *= inv; v.w *= inv;
  *(float4*)p = v;
}

// ---------------- attention, split-K over KV (S=2) -------------------------------
// Scores bounded: |q_hat . k_hat| * SCALE <= 0.1768 -> exp(s) in [0.84,1.19].
// No running max needed; partials (l, o) combine by pure addition.
__global__ __launch_bounds__(256) void attn_k(const float* __restrict__ qkv,
                                              float* __restrict__ po,
                                              float* __restrict__ pl) {
  __shared__ float Kt[64][32];
  __shared__ float Vt[64][32];
  const int bh = blockIdx.y;                 // 0..63
  const int chunk = blockIdx.x >> 1;         // 0..3  (q-row group)
  const int split = blockIdx.x & (SPLITS - 1);  // 0..1 (kv split)
  const int b = bh >> 3, h = bh & 7;
  const int row = (chunk << 8) + threadIdx.x;
  const float* qp = qkv + (size_t)(b * NTOK + row) * QKVN + h * HDIM;
  float q[32];
#pragma unroll
  for (int d4 = 0; d4 < 32; d4 += 4) {
    float4 v = *(const float4*)(qp + d4);
    q[d4] = v.x; q[d4 + 1] = v.y; q[d4 + 2] = v.z; q[d4 + 3] = v.w;
  }
  float ss = 0.f;
#pragma unroll
  for (int d = 0; d < 32; d++) ss += q[d] * q[d];
  float scl = 0.17677669529663687f / fmaxf(sqrtf(ss), 1e-12f);
#pragma unroll
  for (int d = 0; d < 32; d++) q[d] *= scl;

  float l = 0.f;
  float o[32];
#pragma unroll
  for (int d = 0; d < 32; d++) o[d] = 0.f;

  const float* kvbase = qkv + (size_t)(b * NTOK) * QKVN + 256 + h * HDIM;
  constexpr int TPS = 16 / SPLITS;           // tiles per split
  for (int tile = split * TPS; tile < split * TPS + TPS; tile++) {
    __syncthreads();
    for (int e = threadIdx.x; e < 512; e += 256) {
      int jr = e >> 3, d4 = (e & 7) << 2;
      const float* kp = kvbase + (size_t)(tile * 64 + jr) * QKVN + d4;
      *(float4*)&Kt[jr][d4] = *(const float4*)kp;
      *(float4*)&Vt[jr][d4] = *(const float4*)(kp + 256);
    }
    __syncthreads();
#pragma unroll 2
    for (int kk = 0; kk < 64; kk++) {
      float s = 0.f;
#pragma unroll
      for (int d4 = 0; d4 < 32; d4 += 4) {
        float4 kv = *(const float4*)&Kt[kk][d4];
        s += q[d4] * kv.x + q[d4 + 1] * kv.y + q[d4 + 2] * kv.z + q[d4 + 3] * kv.w;
      }
      float p = __expf(s);
      l += p;
#pragma unroll
      for (int d4 = 0; d4 < 32; d4 += 4) {
        float4 vv = *(const float4*)&Vt[kk][d4];
        o[d4] += p * vv.x; o[d4 + 1] += p * vv.y;
        o[d4 + 2] += p * vv.z; o[d4 + 3] += p * vv.w;
      }
    }
  }
  size_t base = ((size_t)(bh * SPLITS + split) << 10) + row;
  pl[base] = l;
  float* op = po + base * 32;
#pragma unroll
  for (int d4 = 0; d4 < 32; d4 += 4) {
    float4 v = {o[d4], o[d4 + 1], o[d4 + 2], o[d4 + 3]};
    *(float4*)(op + d4) = v;
  }
}

// ---------------- combine split-K partials -> [B,N,C] rows ------------------------
__global__ void attn_combine_k(const float* __restrict__ po, const float* __restrict__ pl,
                               float* __restrict__ obuf) {
  int r = blockIdx.x;          // token row 0..8191
  int t = threadIdx.x;         // h = t>>5, d = t&31
  int b = r >> 10, row = r & 1023;
  int bh = b * 8 + (t >> 5);
  float o = 0.f, l = 0.f;
#pragma unroll
  for (int s = 0; s < SPLITS; s++) {
    size_t base = ((size_t)(bh * SPLITS + s) << 10) + row;
    o += po[base * 32 + (t & 31)];
    l += pl[base];
  }
  obuf[(size_t)r * 256 + t] = o / l;
}

// ---------------- per-row (channel) LayerNorm + GELU, one row per wave ------------
__global__ void ln_gelu_k(const float* __restrict__ in, const float* __restrict__ g,
                          const float* __restrict__ bb, float* __restrict__ out) {
  int t = threadIdx.x;
  int lane = t & 63;
  int r = blockIdx.x * 4 + (t >> 6);
  const float* p = in + ((size_t)r << 8) + (lane << 2);
  float4 v = *(const float4*)p;
  float s1 = v.x + v.y + v.z + v.w;
  float s2 = v.x * v.x + v.y * v.y + v.z * v.z + v.w * v.w;
#pragma unroll
  for (int m = 1; m < 64; m <<= 1) {
    s1 += __shfl_xor(s1, m, 64);
    s2 += __shfl_xor(s2, m, 64);
  }
  float mu = s1 * (1.f / 256.f);
  float var = s2 * (1.f / 256.f) - mu * mu;
  float rstd = rsqrtf(var + 1e-5f);
  float4 gv = *(const float4*)(g + (lane << 2));
  float4 bv = *(const float4*)(bb + (lane << 2));
  float4 ov;
  ov.x = gelu_f((v.x - mu) * rstd * gv.x + bv.x);
  ov.y = gelu_f((v.y - mu) * rstd * gv.y + bv.y);
  ov.z = gelu_f((v.z - mu) * rstd * gv.z + bv.z);
  ov.w = gelu_f((v.w - mu) * rstd * gv.w + bv.w);
  *(float4*)(out + ((size_t)r << 8) + (lane << 2)) = ov;
}

// ---------------- [B,HW,C] -> NCHW transpose + identity add ----------------------
__global__ void trans_add_k(const float* __restrict__ m2, const float* __restrict__ x,
                            float* __restrict__ out) {
  __shared__ float tile[32][33];
  int b = blockIdx.z, c0 = blockIdx.y << 5, s0 = blockIdx.x << 5;
  int t = threadIdx.x;
  int j = t & 31, i0 = t >> 5;
#pragma unroll
  for (int i = i0; i < 32; i += 8)
    tile[i][j] = m2[(size_t)(b * 1024 + s0 + i) * 256 + c0 + j];
  __syncthreads();
#pragma unroll
  for (int i2 = i0; i2 < 32; i2 += 8) {
    size_t idx = ((size_t)(b * 256 + c0 + i2) << 10) + s0 + j;
    out[idx] = x[idx] + tile[j][i2];
  }
}

extern "C" void kernel_launch(void* const* d_in, const int* in_sizes, int n_in,
                              void* d_out, int out_size, void* d_ws, size_t ws_size,
                              hipStream_t stream) {
  const float* x     = (const float*)d_in[0];
  const float* dw_w  = (const float*)d_in[1];
  const float* dw_b  = (const float*)d_in[2];
  const float* qkv_w = (const float*)d_in[3];
  const float* c1_w  = (const float*)d_in[4];
  const float* c1_b  = (const float*)d_in[5];
  const float* ln1_g = (const float*)d_in[6];
  const float* ln1_b = (const float*)d_in[7];
  const float* c2_w  = (const float*)d_in[8];
  const float* c2_b  = (const float*)d_in[9];
  const float* ln2_g = (const float*)d_in[10];
  const float* ln2_b = (const float*)d_in[11];
  float* out = (float*)d_out;

  float* ws = (float*)d_ws;
  const size_t MF = (size_t)1 << 20;   // 1M floats = 4 MB
  // Lifetime-checked, non-overlapping-while-live. Peak 12.125 MF = 48.5 MB
  // (round-2's 53 MB layout is known to run; round-3's 65 MB suspected ws overflow).
  //   y2   [0,2M)        dead after qkv-gemm
  //   qkv  [2M,8M)       6M floats exactly; dead after attn_k
  //   po   [8M,12M)      64bh x 2 splits x 1024 x 32 = 4M; dead after combine
  //   pl   [12M,12.125M) 128K floats
  float* y2   = ws;                    // [0, 2M)
  float* qkv  = ws + 2 * MF;           // [2M, 8M)
  float* po   = ws + 8 * MF;           // [8M, 12M)
  float* pl   = ws + 12 * MF;          // [12M, 12.125M)
  float* obuf = ws;                    // [0, 2M)   reuse y2
  float* buf1 = ws + 2 * MF;           // [2M, 4M)  reuse dead qkv
  float* m1   = ws + 4 * MF;           // [4M, 6M)
  float* buf2 = ws + 6 * MF;           // [6M, 8M)
  float* m2b  = ws + 8 * MF;           // [8M, 10M) reuse dead po
  (void)in_sizes; (void)n_in; (void)out_size; (void)ws_size;

  dwconv_k<<<2048, 256, 0, stream>>>(x, dw_w, dw_b, y2);
  gemm_k<128, 128, 8, 8, true, false><<<dim3(6, 64), 256, 0, stream>>>(y2, qkv_w, nullptr, qkv, 768);
  l2k_k<<<2048, 256, 0, stream>>>(qkv);
  attn_k<<<dim3(4 * SPLITS, 64), 256, 0, stream>>>(qkv, po, pl);
  attn_combine_k<<<8192, 256, 0, stream>>>(po, pl, obuf);
  gemm_k<128, 64, 8, 4, false, true><<<dim3(4, 64), 256, 0, stream>>>(obuf, c1_w, c1_b, buf1, 256);
  ln_gelu_k<<<2048, 256, 0, stream>>>(buf1, ln1_g, ln1_b, m1);
  gemm_k<128, 64, 8, 4, false, true><<<dim3(4, 64), 256, 0, stream>>>(m1, c2_w, c2_b, buf2, 256);
  ln_gelu_k<<<2048, 256, 0, stream>>>(buf2, ln2_g, ln2_b, m2b);
  trans_add_k<<<dim3(32, 8, 8), 256, 0, stream>>>(m2b, x, out);
}

// Round 7
// 260.210 us; speedup vs baseline: 1.6856x; 1.6856x over previous
//
#include <hip/hip_runtime.h>
#include <math.h>

#define DIMC 256
#define NTOK 1024   // H*W
#define QKVN 768
#define HDIM 32

typedef __attribute__((ext_vector_type(8))) short bf16x8;
typedef __attribute__((ext_vector_type(4))) float f32x4;
typedef __attribute__((ext_vector_type(4))) unsigned short us4;

__device__ __forceinline__ unsigned short f2bf(float f) {
  unsigned u = __float_as_uint(f);
  u += 0x7FFF + ((u >> 16) & 1);          // round-to-nearest-even
  return (unsigned short)(u >> 16);
}

__device__ __forceinline__ float gelu_f(float y) {
  return 0.5f * y * (1.f + erff(y * 0.70710678118654752f));
}

// ---------------- depthwise 3x3, NCHW -> NCHW ----------------
__global__ void dwconv_k(const float* __restrict__ x, const float* __restrict__ w,
                         const float* __restrict__ b, float* __restrict__ y) {
  int bc = blockIdx.x;              // b*256 + c
  int c = bc & (DIMC - 1);
  float wr[9];
#pragma unroll
  for (int i = 0; i < 9; i++) wr[i] = w[c * 9 + i];
  float bb = b[c];
  const float* xp = x + (size_t)bc * NTOK;
  float* yp = y + (size_t)bc * NTOK;
  for (int p = threadIdx.x; p < NTOK; p += 256) {
    int hh = p >> 5, ww = p & 31;
    float acc = bb;
#pragma unroll
    for (int dh = 0; dh < 3; dh++) {
      int h2 = hh + dh - 1;
      if ((unsigned)h2 < 32u) {
#pragma unroll
        for (int dw = 0; dw < 3; dw++) {
          int w2 = ww + dw - 1;
          if ((unsigned)w2 < 32u) acc += xp[h2 * 32 + w2] * wr[dh * 3 + dw];
        }
      }
    }
    yp[p] = acc;
  }
}

// ---------------- tiled fp32 GEMM: C[M,N] = A[M,K=256] * W[N,K=256]^T (+bias) ----
template <int BM, int BN, int TM, int TN, bool AT, bool BIAS>
__global__ __launch_bounds__(256) void gemm_k(const float* __restrict__ A,
                                              const float* __restrict__ W,
                                              const float* __restrict__ bias,
                                              float* __restrict__ C, int N) {
  constexpr int KB = 16;
  __shared__ float As[KB][BM];
  __shared__ float Bs[KB][BN];
  static_assert((BM / TM) * (BN / TN) == 256, "thread grid");
  const int t = threadIdx.x;
  const int m0 = blockIdx.y * BM;
  const int n0 = blockIdx.x * BN;
  constexpr int NTC = BN / TN;
  const int tr = (t / NTC) * TM;
  const int tc = (t % NTC) * TN;
  float acc[TM][TN] = {};
  for (int k0 = 0; k0 < 256; k0 += KB) {
    __syncthreads();
    if (AT) {
      constexpr int RPK = BM / 4;
      constexpr int LD = (KB * RPK) / 256;
      int b = m0 >> 10;
      int hw0 = m0 & 1023;
#pragma unroll
      for (int u = 0; u < LD; u++) {
        int f = t + u * 256;
        int k = f / RPK;
        int r4 = (f % RPK) * 4;
        float4 v = *(const float4*)(A + ((size_t)(b * 256 + k0 + k) << 10) + hw0 + r4);
        *(float4*)&As[k][r4] = v;
      }
    } else {
      constexpr int LD = (BM * KB / 4) / 256;
#pragma unroll
      for (int u = 0; u < LD; u++) {
        int f = t + u * 256;
        int r = f >> 2;
        int k4 = (f & 3) << 2;
        float4 v = *(const float4*)(A + (size_t)(m0 + r) * 256 + k0 + k4);
        As[k4 + 0][r] = v.x; As[k4 + 1][r] = v.y;
        As[k4 + 2][r] = v.z; As[k4 + 3][r] = v.w;
      }
    }
    {
      constexpr int LD = (BN * KB / 4) / 256;
#pragma unroll
      for (int u = 0; u < LD; u++) {
        int f = t + u * 256;
        int o = f >> 2;
        int k4 = (f & 3) << 2;
        float4 v = *(const float4*)(W + (size_t)(n0 + o) * 256 + k0 + k4);
        Bs[k4 + 0][o] = v.x; Bs[k4 + 1][o] = v.y;
        Bs[k4 + 2][o] = v.z; Bs[k4 + 3][o] = v.w;
      }
    }
    __syncthreads();
#pragma unroll
    for (int kk = 0; kk < KB; kk++) {
      float a[TM], bv[TN];
#pragma unroll
      for (int i = 0; i < TM; i += 4) *(float4*)&a[i] = *(const float4*)&As[kk][tr + i];
#pragma unroll
      for (int j = 0; j < TN; j += 4) *(float4*)&bv[j] = *(const float4*)&Bs[kk][tc + j];
#pragma unroll
      for (int i = 0; i < TM; i++)
#pragma unroll
        for (int j = 0; j < TN; j++) acc[i][j] += a[i] * bv[j];
    }
  }
#pragma unroll
  for (int i = 0; i < TM; i++) {
#pragma unroll
    for (int j = 0; j < TN; j += 4) {
      float4 v = {acc[i][j], acc[i][j + 1], acc[i][j + 2], acc[i][j + 3]};
      if (BIAS) {
        v.x += bias[n0 + tc + j + 0]; v.y += bias[n0 + tc + j + 1];
        v.z += bias[n0 + tc + j + 2]; v.w += bias[n0 + tc + j + 3];
      }
      *(float4*)(C + (size_t)(m0 + tr + i) * N + n0 + tc + j) = v;
    }
  }
}

// ---------------- qkv fp32 -> head-major bf16 Q (l2norm*SCALE), K (l2norm), V ----
// Layout: Qb/Kb/Vb[(b*8+h)*1024 + n][32]
__global__ void cvt_qkv_k(const float* __restrict__ qkv,
                          unsigned short* __restrict__ Qb,
                          unsigned short* __restrict__ Kb,
                          unsigned short* __restrict__ Vb) {
  int n = blockIdx.x;              // 0..8191
  int t = threadIdx.x;
  int b = n >> 10, nr = n & 1023;
  int sec = t >> 6, lane = t & 63;
  if (sec < 2) {
    // q (sec 0) or k (sec 1): 64 lanes x float4 = 256 ch; head = 8 lanes
    const float* p = qkv + (size_t)n * QKVN + sec * 256 + lane * 4;
    float4 v = *(const float4*)p;
    float s = v.x * v.x + v.y * v.y + v.z * v.z + v.w * v.w;
    s += __shfl_xor(s, 1, 64); s += __shfl_xor(s, 2, 64); s += __shfl_xor(s, 4, 64);
    float inv = 1.f / fmaxf(sqrtf(s), 1e-12f);
    if (sec == 0) inv *= 0.17677669529663687f;   // fold softmax scale into q
    int h = lane >> 3, d4 = (lane & 7) << 2;
    unsigned short* dst = (sec == 0 ? Qb : Kb) + ((size_t)((b * 8 + h) * 1024 + nr)) * 32 + d4;
    us4 o = {f2bf(v.x * inv), f2bf(v.y * inv), f2bf(v.z * inv), f2bf(v.w * inv)};
    *(us4*)dst = o;
  } else {
    // v: threads 128..255, 2 elems each
    int i = t - 128;
    const float* p = qkv + (size_t)n * QKVN + 512 + i * 2;
    float2 v = *(const float2*)p;
    int c = i * 2;
    int h = c >> 5, d = c & 31;
    unsigned short* dst = Vb + ((size_t)((b * 8 + h) * 1024 + nr)) * 32 + d;
    ushort2 o = {f2bf(v.x), f2bf(v.y)};
    *(ushort2*)dst = o;
  }
}

// ---------------- MFMA bf16 flash attention (no-max variant) ---------------------
// Scores bounded |s|<=0.1768 (q,k unit vectors, SCALE folded) -> exp(s) in [.84,1.19]:
// no running max; l,o accumulate additively.
// Block: (bh, 64-q-chunk), 128 threads = 2 waves x 32 q-rows. KV step = 32.
#define PSTR 56   // LDS row stride in shorts (112 B: 16B-aligned rows, 2-way conflicts)

__global__ __launch_bounds__(128) void attn_mfma_k(const unsigned short* __restrict__ Qb,
                                                   const unsigned short* __restrict__ Kb,
                                                   const unsigned short* __restrict__ Vb,
                                                   float* __restrict__ obuf) {
  __shared__ unsigned short Vt[32 * PSTR];       // V^T tile [d][kv]
  __shared__ unsigned short Pl[2][32 * PSTR];    // per-wave P [q][kv]
  const int bh = blockIdx.y;
  const int chunk = blockIdx.x;                  // 0..15
  const int tid = threadIdx.x;
  const int wid = tid >> 6, lane = tid & 63;
  const int lg = lane >> 4, lr = lane & 15;
  const int q0 = chunk * 64 + wid * 32;
  const size_t base = (size_t)bh * NTOK;

  // Q A-frags (2 q-tiles of 16 rows), loop-invariant; lane: row=lr, k=lg*8..+7
  bf16x8 qf[2];
#pragma unroll
  for (int qt = 0; qt < 2; qt++)
    qf[qt] = *(const bf16x8*)(Qb + (base + q0 + qt * 16 + lr) * 32 + lg * 8);

  f32x4 o[2][2] = {};        // o[qt][dt]: rows q=16qt+4lg+r, cols d=16dt+lr
  float lpart[2][4] = {};

  for (int step = 0; step < 32; step++) {
    const int kv0 = step * 32;
    __syncthreads();                             // prior step's Vt reads done
    {  // stage V^T: 128 threads x 8 bf16
      int kv = tid >> 2, d0 = (tid & 3) * 8;
      bf16x8 v = *(const bf16x8*)(Vb + (base + kv0 + kv) * 32 + d0);
#pragma unroll
      for (int i = 0; i < 8; i++) Vt[(d0 + i) * PSTR + kv] = (unsigned short)v[i];
    }
    __syncthreads();
    // K B-frags: lane: col(kv)=lr, k=d=lg*8..+7
    bf16x8 kf[2];
#pragma unroll
    for (int ct = 0; ct < 2; ct++)
      kf[ct] = *(const bf16x8*)(Kb + (base + kv0 + ct * 16 + lr) * 32 + lg * 8);
    // S = Q*K^T -> P = exp(S) -> P_lds (per-wave, no barrier needed)
    unsigned short* pw = &Pl[wid][0];
#pragma unroll
    for (int qt = 0; qt < 2; qt++) {
#pragma unroll
      for (int ct = 0; ct < 2; ct++) {
        f32x4 c = {};
        c = __builtin_amdgcn_mfma_f32_16x16x32_bf16(qf[qt], kf[ct], c, 0, 0, 0);
#pragma unroll
        for (int r = 0; r < 4; r++) {
          float p = __expf(c[r]);
          lpart[qt][r] += p;
          pw[(qt * 16 + lg * 4 + r) * PSTR + ct * 16 + lr] = f2bf(p);
        }
      }
    }
    // O += P*V: A=P (row=q, k=kv), B=V^T-as-B (col=d, k=kv)
#pragma unroll
    for (int qt = 0; qt < 2; qt++) {
      bf16x8 pf = *(const bf16x8*)(pw + (qt * 16 + lr) * PSTR + lg * 8);
#pragma unroll
      for (int dt = 0; dt < 2; dt++) {
        bf16x8 vf = *(const bf16x8*)(&Vt[(dt * 16 + lr) * PSTR + lg * 8]);
        o[qt][dt] = __builtin_amdgcn_mfma_f32_16x16x32_bf16(pf, vf, o[qt][dt], 0, 0, 0);
      }
    }
  }
  // l: reduce across the 16 lanes (lr) sharing each (lg, r) row
#pragma unroll
  for (int qt = 0; qt < 2; qt++) {
#pragma unroll
    for (int r = 0; r < 4; r++) {
      float l = lpart[qt][r];
      l += __shfl_xor(l, 1, 64); l += __shfl_xor(l, 2, 64);
      l += __shfl_xor(l, 4, 64); l += __shfl_xor(l, 8, 64);
      lpart[qt][r] = 1.f / l;
    }
  }
  const int b = bh >> 3, h = bh & 7;
#pragma unroll
  for (int qt = 0; qt < 2; qt++)
#pragma unroll
    for (int dt = 0; dt < 2; dt++)
#pragma unroll
      for (int r = 0; r < 4; r++) {
        int q = q0 + qt * 16 + lg * 4 + r;
        int c = h * 32 + dt * 16 + lr;
        obuf[((size_t)(b * NTOK + q)) * DIMC + c] = o[qt][dt][r] * lpart[qt][r];
      }
}

// ---------------- per-row (channel) LayerNorm + GELU, one row per wave ------------
__global__ void ln_gelu_k(const float* __restrict__ in, const float* __restrict__ g,
                          const float* __restrict__ bb, float* __restrict__ out) {
  int t = threadIdx.x;
  int lane = t & 63;
  int r = blockIdx.x * 4 + (t >> 6);
  const float* p = in + ((size_t)r << 8) + (lane << 2);
  float4 v = *(const float4*)p;
  float s1 = v.x + v.y + v.z + v.w;
  float s2 = v.x * v.x + v.y * v.y + v.z * v.z + v.w * v.w;
#pragma unroll
  for (int m = 1; m < 64; m <<= 1) {
    s1 += __shfl_xor(s1, m, 64);
    s2 += __shfl_xor(s2, m, 64);
  }
  float mu = s1 * (1.f / 256.f);
  float var = s2 * (1.f / 256.f) - mu * mu;
  float rstd = rsqrtf(var + 1e-5f);
  float4 gv = *(const float4*)(g + (lane << 2));
  float4 bv = *(const float4*)(bb + (lane << 2));
  float4 ov;
  ov.x = gelu_f((v.x - mu) * rstd * gv.x + bv.x);
  ov.y = gelu_f((v.y - mu) * rstd * gv.y + bv.y);
  ov.z = gelu_f((v.z - mu) * rstd * gv.z + bv.z);
  ov.w = gelu_f((v.w - mu) * rstd * gv.w + bv.w);
  *(float4*)(out + ((size_t)r << 8) + (lane << 2)) = ov;
}

// ---------------- [B,HW,C] -> NCHW transpose + identity add ----------------------
__global__ void trans_add_k(const float* __restrict__ m2, const float* __restrict__ x,
                            float* __restrict__ out) {
  __shared__ float tile[32][33];
  int b = blockIdx.z, c0 = blockIdx.y << 5, s0 = blockIdx.x << 5;
  int t = threadIdx.x;
  int j = t & 31, i0 = t >> 5;
#pragma unroll
  for (int i = i0; i < 32; i += 8)
    tile[i][j] = m2[(size_t)(b * 1024 + s0 + i) * 256 + c0 + j];
  __syncthreads();
#pragma unroll
  for (int i2 = i0; i2 < 32; i2 += 8) {
    size_t idx = ((size_t)(b * 256 + c0 + i2) << 10) + s0 + j;
    out[idx] = x[idx] + tile[j][i2];
  }
}

extern "C" void kernel_launch(void* const* d_in, const int* in_sizes, int n_in,
                              void* d_out, int out_size, void* d_ws, size_t ws_size,
                              hipStream_t stream) {
  const float* x     = (const float*)d_in[0];
  const float* dw_w  = (const float*)d_in[1];
  const float* dw_b  = (const float*)d_in[2];
  const float* qkv_w = (const float*)d_in[3];
  const float* c1_w  = (const float*)d_in[4];
  const float* c1_b  = (const float*)d_in[5];
  const float* ln1_g = (const float*)d_in[6];
  const float* ln1_b = (const float*)d_in[7];
  const float* c2_w  = (const float*)d_in[8];
  const float* c2_b  = (const float*)d_in[9];
  const float* ln2_g = (const float*)d_in[10];
  const float* ln2_b = (const float*)d_in[11];
  float* out = (float*)d_out;

  float* ws = (float*)d_ws;
  const size_t MF = (size_t)1 << 20;   // 1M floats = 4 MB
  // Lifetimes (peak 11 MF = 44 MB, < 48.5 MB proven-safe):
  //   y2  [0,2M)  dead after qkv-gemm;  qkv [2M,8M) dead after cvt;
  //   Qb [8M,9M) Kb [9M,10M) Vb [10M,11M) (bf16, dead after attn)
  //   obuf=[0,2M); buf1 [2M,4M); m1 [4M,6M); buf2 [6M,8M); m2b [8M,10M)
  float* y2   = ws;
  float* qkv  = ws + 2 * MF;
  unsigned short* Qb = (unsigned short*)(ws + 8 * MF);
  unsigned short* Kb = (unsigned short*)(ws + 9 * MF);
  unsigned short* Vb = (unsigned short*)(ws + 10 * MF);
  float* obuf = ws;
  float* buf1 = ws + 2 * MF;
  float* m1   = ws + 4 * MF;
  float* buf2 = ws + 6 * MF;
  float* m2b  = ws + 8 * MF;
  (void)in_sizes; (void)n_in; (void)out_size; (void)ws_size;

  dwconv_k<<<2048, 256, 0, stream>>>(x, dw_w, dw_b, y2);
  gemm_k<128, 128, 8, 8, true, false><<<dim3(6, 64), 256, 0, stream>>>(y2, qkv_w, nullptr, qkv, 768);
  cvt_qkv_k<<<8192, 256, 0, stream>>>(qkv, Qb, Kb, Vb);
  attn_mfma_k<<<dim3(16, 64), 128, 0, stream>>>(Qb, Kb, Vb, obuf);
  gemm_k<128, 64, 8, 4, false, true><<<dim3(4, 64), 256, 0, stream>>>(obuf, c1_w, c1_b, buf1, 256);
  ln_gelu_k<<<2048, 256, 0, stream>>>(buf1, ln1_g, ln1_b, m1);
  gemm_k<128, 64, 8, 4, false, true><<<dim3(4, 64), 256, 0, stream>>>(m1, c2_w, c2_b, buf2, 256);
  ln_gelu_k<<<2048, 256, 0, stream>>>(buf2, ln2_g, ln2_b, m2b);
  trans_add_k<<<dim3(32, 8, 8), 256, 0, stream>>>(m2b, x, out);
}

// Round 9
// 185.197 us; speedup vs baseline: 2.3684x; 1.4050x over previous
//
#include <hip/hip_runtime.h>
#include <math.h>

#define DIMC 256
#define NTOK 1024   // H*W
#define QKVN 768
#define HDIM 32

typedef __attribute__((ext_vector_type(8))) short bf16x8;
typedef __attribute__((ext_vector_type(4))) float f32x4;
typedef __attribute__((ext_vector_type(4))) unsigned short us4;

__device__ __forceinline__ unsigned short f2bf(float f) {
  unsigned u = __float_as_uint(f);
  u += 0x7FFF + ((u >> 16) & 1);          // round-to-nearest-even
  return (unsigned short)(u >> 16);
}

__device__ __forceinline__ float gelu_f(float y) {
  return 0.5f * y * (1.f + erff(y * 0.70710678118654752f));
}

// ---------------- depthwise 3x3, NCHW -> NCHW ----------------
__global__ void dwconv_k(const float* __restrict__ x, const float* __restrict__ w,
                         const float* __restrict__ b, float* __restrict__ y) {
  int bc = blockIdx.x;              // b*256 + c
  int c = bc & (DIMC - 1);
  float wr[9];
#pragma unroll
  for (int i = 0; i < 9; i++) wr[i] = w[c * 9 + i];
  float bb = b[c];
  const float* xp = x + (size_t)bc * NTOK;
  float* yp = y + (size_t)bc * NTOK;
  for (int p = threadIdx.x; p < NTOK; p += 256) {
    int hh = p >> 5, ww = p & 31;
    float acc = bb;
#pragma unroll
    for (int dh = 0; dh < 3; dh++) {
      int h2 = hh + dh - 1;
      if ((unsigned)h2 < 32u) {
#pragma unroll
        for (int dw = 0; dw < 3; dw++) {
          int w2 = ww + dw - 1;
          if ((unsigned)w2 < 32u) acc += xp[h2 * 32 + w2] * wr[dh * 3 + dw];
        }
      }
    }
    yp[p] = acc;
  }
}

// ---------------- weights fp32 -> bf16 (qkv_w | c1_w | c2_w concatenated) --------
__global__ void cvt_w_k(const float* __restrict__ w0, const float* __restrict__ w1,
                        const float* __restrict__ w2, unsigned short* __restrict__ Wb) {
  int i = (blockIdx.x * 256 + threadIdx.x) * 4;   // 327680 total elems
  const float* src;
  int off;
  if (i < 196608) { src = w0; off = i; }
  else if (i < 262144) { src = w1; off = i - 196608; }
  else { src = w2; off = i - 262144; }
  float4 v = *(const float4*)(src + off);
  us4 o = {f2bf(v.x), f2bf(v.y), f2bf(v.z), f2bf(v.w)};
  *(us4*)(Wb + i) = o;
}

// ---------------- y2 [B][C][HW] fp32 -> A0 [B][HW][C] bf16 (LDS transpose) -------
__global__ void t2b_k(const float* __restrict__ y2, unsigned short* __restrict__ A0) {
  __shared__ float tile[32][33];
  int b = blockIdx.z, c0 = blockIdx.y << 5, s0 = blockIdx.x << 5;
  int t = threadIdx.x;
  int j = t & 31, i0 = t >> 5;
#pragma unroll
  for (int i = i0; i < 32; i += 8)
    tile[i][j] = y2[(size_t)(b * 256 + c0 + i) * 1024 + s0 + j];
  __syncthreads();
#pragma unroll
  for (int i2 = i0; i2 < 32; i2 += 8)
    A0[(size_t)(b * 1024 + s0 + i2) * 256 + c0 + j] = f2bf(tile[j][i2]);
}

// ---------------- bf16 MFMA GEMM: C[M,N] = A[M,256] * W[N,256]^T (+bias) ---------
// A token-major bf16, W bf16 (k-contiguous). 256 thr = 4 waves (2x2).
// Block tile 128M x 64N; wave tile 64x32 = 4x2 frags of 16x16; K-step 32.
// LDS rows padded to 40 shorts (80 B): frag ds_read_b128 -> 2-way, free.
template <bool BIAS>
__global__ __launch_bounds__(256) void mgemm_k(const unsigned short* __restrict__ A,
                                               const unsigned short* __restrict__ W,
                                               const float* __restrict__ bias,
                                               float* __restrict__ C, int N) {
  __shared__ __align__(16) unsigned short As[128 * 40];
  __shared__ __align__(16) unsigned short Bs[64 * 40];
  const int t = threadIdx.x;
  const int m0 = blockIdx.y * 128;
  const int n0 = blockIdx.x * 64;
  const int wid = t >> 6, lane = t & 63;
  const int lg = lane >> 4, lr = lane & 15;
  const int wm0 = (wid >> 1) * 64, wn0 = (wid & 1) * 32;

  f32x4 acc[4][2] = {};
  for (int k0 = 0; k0 < 256; k0 += 32) {
    __syncthreads();
    {  // stage A tile 128x32: 2 chunks of 8 bf16 per thread
#pragma unroll
      for (int u = 0; u < 2; u++) {
        int f = t + u * 256;
        int r = f >> 2, c = f & 3;
        bf16x8 v = *(const bf16x8*)(A + (size_t)(m0 + r) * 256 + k0 + c * 8);
        *(bf16x8*)&As[r * 40 + c * 8] = v;
      }
      // stage B tile 64x32: 1 chunk per thread
      int o = t >> 2, c = t & 3;
      bf16x8 v = *(const bf16x8*)(W + (size_t)(n0 + o) * 256 + k0 + c * 8);
      *(bf16x8*)&Bs[o * 40 + c * 8] = v;
    }
    __syncthreads();
    bf16x8 af[4], bfr[2];
#pragma unroll
    for (int mt = 0; mt < 4; mt++)
      af[mt] = *(const bf16x8*)&As[(wm0 + mt * 16 + lr) * 40 + lg * 8];
#pragma unroll
    for (int nt = 0; nt < 2; nt++)
      bfr[nt] = *(const bf16x8*)&Bs[(wn0 + nt * 16 + lr) * 40 + lg * 8];
#pragma unroll
    for (int mt = 0; mt < 4; mt++)
#pragma unroll
      for (int nt = 0; nt < 2; nt++)
        acc[mt][nt] = __builtin_amdgcn_mfma_f32_16x16x32_bf16(af[mt], bfr[nt], acc[mt][nt], 0, 0, 0);
  }
  float bv[2];
#pragma unroll
  for (int nt = 0; nt < 2; nt++)
    bv[nt] = BIAS ? bias[n0 + wn0 + nt * 16 + lr] : 0.f;
#pragma unroll
  for (int mt = 0; mt < 4; mt++)
#pragma unroll
    for (int nt = 0; nt < 2; nt++)
#pragma unroll
      for (int r = 0; r < 4; r++) {
        int row = m0 + wm0 + mt * 16 + lg * 4 + r;
        int col = n0 + wn0 + nt * 16 + lr;
        C[(size_t)row * N + col] = acc[mt][nt][r] + bv[nt];
      }
}

// ---------------- qkv fp32 -> head-major bf16 Q (l2norm*SCALE), K (l2norm), V ----
// Layout: Qb/Kb/Vb[(b*8+h)*1024 + n][32]
__global__ void cvt_qkv_k(const float* __restrict__ qkv,
                          unsigned short* __restrict__ Qb,
                          unsigned short* __restrict__ Kb,
                          unsigned short* __restrict__ Vb) {
  int n = blockIdx.x;              // 0..8191
  int t = threadIdx.x;
  int b = n >> 10, nr = n & 1023;
  int sec = t >> 6, lane = t & 63;
  if (sec < 2) {
    const float* p = qkv + (size_t)n * QKVN + sec * 256 + lane * 4;
    float4 v = *(const float4*)p;
    float s = v.x * v.x + v.y * v.y + v.z * v.z + v.w * v.w;
    s += __shfl_xor(s, 1, 64); s += __shfl_xor(s, 2, 64); s += __shfl_xor(s, 4, 64);
    float inv = 1.f / fmaxf(sqrtf(s), 1e-12f);
    if (sec == 0) inv *= 0.17677669529663687f;   // fold softmax scale into q
    int h = lane >> 3, d4 = (lane & 7) << 2;
    unsigned short* dst = (sec == 0 ? Qb : Kb) + ((size_t)((b * 8 + h) * 1024 + nr)) * 32 + d4;
    us4 o = {f2bf(v.x * inv), f2bf(v.y * inv), f2bf(v.z * inv), f2bf(v.w * inv)};
    *(us4*)dst = o;
  } else {
    int i = t - 128;
    const float* p = qkv + (size_t)n * QKVN + 512 + i * 2;
    float2 v = *(const float2*)p;
    int c = i * 2;
    int h = c >> 5, d = c & 31;
    unsigned short* dst = Vb + ((size_t)((b * 8 + h) * 1024 + nr)) * 32 + d;
    ushort2 o = {f2bf(v.x), f2bf(v.y)};
    *(ushort2*)dst = o;
  }
}

// ---------------- MFMA bf16 flash attention (no-max variant), bf16 out -----------
#define PSTR 56   // LDS row stride in shorts

__global__ __launch_bounds__(128) void attn_mfma_k(const unsigned short* __restrict__ Qb,
                                                   const unsigned short* __restrict__ Kb,
                                                   const unsigned short* __restrict__ Vb,
                                                   unsigned short* __restrict__ obuf) {
  __shared__ unsigned short Vt[32 * PSTR];       // V^T tile [d][kv]
  __shared__ unsigned short Pl[2][32 * PSTR];    // per-wave P [q][kv]
  const int bh = blockIdx.y;
  const int chunk = blockIdx.x;                  // 0..15
  const int tid = threadIdx.x;
  const int wid = tid >> 6, lane = tid & 63;
  const int lg = lane >> 4, lr = lane & 15;
  const int q0 = chunk * 64 + wid * 32;
  const size_t base = (size_t)bh * NTOK;

  bf16x8 qf[2];
#pragma unroll
  for (int qt = 0; qt < 2; qt++)
    qf[qt] = *(const bf16x8*)(Qb + (base + q0 + qt * 16 + lr) * 32 + lg * 8);

  f32x4 o[2][2] = {};
  float lpart[2][4] = {};

  for (int step = 0; step < 32; step++) {
    const int kv0 = step * 32;
    __syncthreads();
    {  // stage V^T
      int kv = tid >> 2, d0 = (tid & 3) * 8;
      bf16x8 v = *(const bf16x8*)(Vb + (base + kv0 + kv) * 32 + d0);
#pragma unroll
      for (int i = 0; i < 8; i++) Vt[(d0 + i) * PSTR + kv] = (unsigned short)v[i];
    }
    __syncthreads();
    bf16x8 kf[2];
#pragma unroll
    for (int ct = 0; ct < 2; ct++)
      kf[ct] = *(const bf16x8*)(Kb + (base + kv0 + ct * 16 + lr) * 32 + lg * 8);
    unsigned short* pw = &Pl[wid][0];
#pragma unroll
    for (int qt = 0; qt < 2; qt++) {
#pragma unroll
      for (int ct = 0; ct < 2; ct++) {
        f32x4 c = {};
        c = __builtin_amdgcn_mfma_f32_16x16x32_bf16(qf[qt], kf[ct], c, 0, 0, 0);
#pragma unroll
        for (int r = 0; r < 4; r++) {
          float p = __expf(c[r]);
          lpart[qt][r] += p;
          pw[(qt * 16 + lg * 4 + r) * PSTR + ct * 16 + lr] = f2bf(p);
        }
      }
    }
#pragma unroll
    for (int qt = 0; qt < 2; qt++) {
      bf16x8 pf = *(const bf16x8*)(pw + (qt * 16 + lr) * PSTR + lg * 8);
#pragma unroll
      for (int dt = 0; dt < 2; dt++) {
        bf16x8 vf = *(const bf16x8*)(&Vt[(dt * 16 + lr) * PSTR + lg * 8]);
        o[qt][dt] = __builtin_amdgcn_mfma_f32_16x16x32_bf16(pf, vf, o[qt][dt], 0, 0, 0);
      }
    }
  }
#pragma unroll
  for (int qt = 0; qt < 2; qt++) {
#pragma unroll
    for (int r = 0; r < 4; r++) {
      float l = lpart[qt][r];
      l += __shfl_xor(l, 1, 64); l += __shfl_xor(l, 2, 64);
      l += __shfl_xor(l, 4, 64); l += __shfl_xor(l, 8, 64);
      lpart[qt][r] = 1.f / l;
    }
  }
  const int b = bh >> 3, h = bh & 7;
#pragma unroll
  for (int qt = 0; qt < 2; qt++)
#pragma unroll
    for (int dt = 0; dt < 2; dt++)
#pragma unroll
      for (int r = 0; r < 4; r++) {
        int q = q0 + qt * 16 + lg * 4 + r;
        int c = h * 32 + dt * 16 + lr;
        obuf[((size_t)(b * NTOK + q)) * DIMC + c] = f2bf(o[qt][dt][r] * lpart[qt][r]);
      }
}

// ---------------- per-row (channel) LayerNorm + GELU, one row per wave ------------
template <bool OBF>
__global__ void ln_gelu_k(const float* __restrict__ in, const float* __restrict__ g,
                          const float* __restrict__ bb, void* __restrict__ outv) {
  int t = threadIdx.x;
  int lane = t & 63;
  int r = blockIdx.x * 4 + (t >> 6);
  const float* p = in + ((size_t)r << 8) + (lane << 2);
  float4 v = *(const float4*)p;
  float s1 = v.x + v.y + v.z + v.w;
  float s2 = v.x * v.x + v.y * v.y + v.z * v.z + v.w * v.w;
#pragma unroll
  for (int m = 1; m < 64; m <<= 1) {
    s1 += __shfl_xor(s1, m, 64);
    s2 += __shfl_xor(s2, m, 64);
  }
  float mu = s1 * (1.f / 256.f);
  float var = s2 * (1.f / 256.f) - mu * mu;
  float rstd = rsqrtf(var + 1e-5f);
  float4 gv = *(const float4*)(g + (lane << 2));
  float4 bv = *(const float4*)(bb + (lane << 2));
  float4 ov;
  ov.x = gelu_f((v.x - mu) * rstd * gv.x + bv.x);
  ov.y = gelu_f((v.y - mu) * rstd * gv.y + bv.y);
  ov.z = gelu_f((v.z - mu) * rstd * gv.z + bv.z);
  ov.w = gelu_f((v.w - mu) * rstd * gv.w + bv.w);
  if (OBF) {
    us4 ob = {f2bf(ov.x), f2bf(ov.y), f2bf(ov.z), f2bf(ov.w)};
    *(us4*)((unsigned short*)outv + ((size_t)r << 8) + (lane << 2)) = ob;
  } else {
    *(float4*)((float*)outv + ((size_t)r << 8) + (lane << 2)) = ov;
  }
}

// ---------------- [B,HW,C] -> NCHW transpose + identity add ----------------------
__global__ void trans_add_k(const float* __restrict__ m2, const float* __restrict__ x,
                            float* __restrict__ out) {
  __shared__ float tile[32][33];
  int b = blockIdx.z, c0 = blockIdx.y << 5, s0 = blockIdx.x << 5;
  int t = threadIdx.x;
  int j = t & 31, i0 = t >> 5;
#pragma unroll
  for (int i = i0; i < 32; i += 8)
    tile[i][j] = m2[(size_t)(b * 1024 + s0 + i) * 256 + c0 + j];
  __syncthreads();
#pragma unroll
  for (int i2 = i0; i2 < 32; i2 += 8) {
    size_t idx = ((size_t)(b * 256 + c0 + i2) << 10) + s0 + j;
    out[idx] = x[idx] + tile[j][i2];
  }
}

extern "C" void kernel_launch(void* const* d_in, const int* in_sizes, int n_in,
                              void* d_out, int out_size, void* d_ws, size_t ws_size,
                              hipStream_t stream) {
  const float* x     = (const float*)d_in[0];
  const float* dw_w  = (const float*)d_in[1];
  const float* dw_b  = (const float*)d_in[2];
  const float* qkv_w = (const float*)d_in[3];
  const float* c1_w  = (const float*)d_in[4];
  const float* c1_b  = (const float*)d_in[5];
  const float* ln1_g = (const float*)d_in[6];
  const float* ln1_b = (const float*)d_in[7];
  const float* c2_w  = (const float*)d_in[8];
  const float* c2_b  = (const float*)d_in[9];
  const float* ln2_g = (const float*)d_in[10];
  const float* ln2_b = (const float*)d_in[11];
  float* out = (float*)d_out;

  float* ws = (float*)d_ws;
  const size_t MF = (size_t)1 << 20;   // 1M floats = 4 MB
  // SIZES (in MF float-units; bf16 buffers count shorts/2):
  //   y2 2 MF | A0 1 MF (2M shorts) | Wb 0.25 MF (327680 shorts -> 0.65 MB)
  //   qkv 6 MF | Qb/Kb/Vb 1 MF EACH (64*1024*32 = 2M shorts = 4 MB each;
  //   round-8 bug: had packed them into 0.125 MF slots -> Qb clobbered Kb/Vb/qkv)
  // Layout (disjoint-while-live; peak 13 MF = 52 MB <= 53 MB proven to run):
  //   y2 [0,2M) dead after t2b | A0 [2M,3M) dead after qkv-gemm | Wb [3M,3.25M)
  //   qkv [4M,10M) dead after cvt_qkv | Qb [10M,11M) Kb [11M,12M) Vb [12M,13M)
  //   obuf bf16 [0,1M) | m1 bf16 [1M,2M) | buf1 [4M,6M) | buf2 [6M,8M) | m2b [8M,10M)
  float* y2   = ws;
  unsigned short* A0 = (unsigned short*)(ws + 2 * MF);
  unsigned short* Wb = (unsigned short*)(ws + 3 * MF);
  float* qkv  = ws + 4 * MF;
  unsigned short* Qb = (unsigned short*)(ws + 10 * MF);
  unsigned short* Kb = (unsigned short*)(ws + 11 * MF);
  unsigned short* Vb = (unsigned short*)(ws + 12 * MF);
  unsigned short* obuf = (unsigned short*)ws;
  unsigned short* m1 = (unsigned short*)(ws + 1 * MF);
  float* buf1 = ws + 4 * MF;
  float* buf2 = ws + 6 * MF;
  float* m2b  = ws + 8 * MF;
  (void)in_sizes; (void)n_in; (void)out_size; (void)ws_size;

  dwconv_k<<<2048, 256, 0, stream>>>(x, dw_w, dw_b, y2);
  cvt_w_k<<<320, 256, 0, stream>>>(qkv_w, c1_w, c2_w, Wb);
  t2b_k<<<dim3(32, 8, 8), 256, 0, stream>>>(y2, A0);
  mgemm_k<false><<<dim3(12, 64), 256, 0, stream>>>(A0, Wb, nullptr, qkv, 768);
  cvt_qkv_k<<<8192, 256, 0, stream>>>(qkv, Qb, Kb, Vb);
  attn_mfma_k<<<dim3(16, 64), 128, 0, stream>>>(Qb, Kb, Vb, obuf);
  mgemm_k<true><<<dim3(4, 64), 256, 0, stream>>>(obuf, Wb + 196608, c1_b, buf1, 256);
  ln_gelu_k<true><<<2048, 256, 0, stream>>>(buf1, ln1_g, ln1_b, m1);
  mgemm_k<true><<<dim3(4, 64), 256, 0, stream>>>(m1, Wb + 262144, c2_b, buf2, 256);
  ln_gelu_k<false><<<2048, 256, 0, stream>>>(buf2, ln2_g, ln2_b, m2b);
  trans_add_k<<<dim3(32, 8, 8), 256, 0, stream>>>(m2b, x, out);
}

// Round 11
// 178.255 us; speedup vs baseline: 2.4606x; 1.0389x over previous
//
#include <hip/hip_runtime.h>
#include <math.h>

#define DIMC 256
#define NTOK 1024   // H*W
#define QKVN 768
#define HDIM 32

typedef __attribute__((ext_vector_type(8))) short bf16x8;
typedef __attribute__((ext_vector_type(4))) float f32x4;
typedef __attribute__((ext_vector_type(4))) unsigned short us4;

__device__ __forceinline__ unsigned short f2bf(float f) {
  unsigned u = __float_as_uint(f);
  u += 0x7FFF + ((u >> 16) & 1);          // round-to-nearest-even
  return (unsigned short)(u >> 16);
}

__device__ __forceinline__ float gelu_f(float y) {
  return 0.5f * y * (1.f + erff(y * 0.70710678118654752f));
}

// ---------------- depthwise 3x3, NCHW -> NCHW ----------------
__global__ void dwconv_k(const float* __restrict__ x, const float* __restrict__ w,
                         const float* __restrict__ b, float* __restrict__ y) {
  int bc = blockIdx.x;              // b*256 + c
  int c = bc & (DIMC - 1);
  float wr[9];
#pragma unroll
  for (int i = 0; i < 9; i++) wr[i] = w[c * 9 + i];
  float bb = b[c];
  const float* xp = x + (size_t)bc * NTOK;
  float* yp = y + (size_t)bc * NTOK;
  for (int p = threadIdx.x; p < NTOK; p += 256) {
    int hh = p >> 5, ww = p & 31;
    float acc = bb;
#pragma unroll
    for (int dh = 0; dh < 3; dh++) {
      int h2 = hh + dh - 1;
      if ((unsigned)h2 < 32u) {
#pragma unroll
        for (int dw = 0; dw < 3; dw++) {
          int w2 = ww + dw - 1;
          if ((unsigned)w2 < 32u) acc += xp[h2 * 32 + w2] * wr[dh * 3 + dw];
        }
      }
    }
    yp[p] = acc;
  }
}

// ---------------- weights fp32 -> bf16 (qkv_w | c1_w | c2_w concatenated) --------
__global__ void cvt_w_k(const float* __restrict__ w0, const float* __restrict__ w1,
                        const float* __restrict__ w2, unsigned short* __restrict__ Wb) {
  int i = (blockIdx.x * 256 + threadIdx.x) * 4;   // 327680 total elems
  const float* src;
  int off;
  if (i < 196608) { src = w0; off = i; }
  else if (i < 262144) { src = w1; off = i - 196608; }
  else { src = w2; off = i - 262144; }
  float4 v = *(const float4*)(src + off);
  us4 o = {f2bf(v.x), f2bf(v.y), f2bf(v.z), f2bf(v.w)};
  *(us4*)(Wb + i) = o;
}

// ---------------- y2 [B][C][HW] fp32 -> A0 [B][HW][C] bf16 (LDS transpose) -------
__global__ void t2b_k(const float* __restrict__ y2, unsigned short* __restrict__ A0) {
  __shared__ float tile[32][33];
  int b = blockIdx.z, c0 = blockIdx.y << 5, s0 = blockIdx.x << 5;
  int t = threadIdx.x;
  int j = t & 31, i0 = t >> 5;
#pragma unroll
  for (int i = i0; i < 32; i += 8)
    tile[i][j] = y2[(size_t)(b * 256 + c0 + i) * 1024 + s0 + j];
  __syncthreads();
#pragma unroll
  for (int i2 = i0; i2 < 32; i2 += 8)
    A0[(size_t)(b * 1024 + s0 + i2) * 256 + c0 + j] = f2bf(tile[j][i2]);
}

// ---------------- bf16 MFMA GEMM: C[M,N] = A[M,256] * W[N,256]^T (+bias) ---------
template <bool BIAS>
__global__ __launch_bounds__(256) void mgemm_k(const unsigned short* __restrict__ A,
                                               const unsigned short* __restrict__ W,
                                               const float* __restrict__ bias,
                                               float* __restrict__ C, int N) {
  __shared__ __align__(16) unsigned short As[128 * 40];
  __shared__ __align__(16) unsigned short Bs[64 * 40];
  const int t = threadIdx.x;
  const int m0 = blockIdx.y * 128;
  const int n0 = blockIdx.x * 64;
  const int wid = t >> 6, lane = t & 63;
  const int lg = lane >> 4, lr = lane & 15;
  const int wm0 = (wid >> 1) * 64, wn0 = (wid & 1) * 32;

  f32x4 acc[4][2] = {};
  for (int k0 = 0; k0 < 256; k0 += 32) {
    __syncthreads();
    {
#pragma unroll
      for (int u = 0; u < 2; u++) {
        int f = t + u * 256;
        int r = f >> 2, c = f & 3;
        bf16x8 v = *(const bf16x8*)(A + (size_t)(m0 + r) * 256 + k0 + c * 8);
        *(bf16x8*)&As[r * 40 + c * 8] = v;
      }
      int o = t >> 2, c = t & 3;
      bf16x8 v = *(const bf16x8*)(W + (size_t)(n0 + o) * 256 + k0 + c * 8);
      *(bf16x8*)&Bs[o * 40 + c * 8] = v;
    }
    __syncthreads();
    bf16x8 af[4], bfr[2];
#pragma unroll
    for (int mt = 0; mt < 4; mt++)
      af[mt] = *(const bf16x8*)&As[(wm0 + mt * 16 + lr) * 40 + lg * 8];
#pragma unroll
    for (int nt = 0; nt < 2; nt++)
      bfr[nt] = *(const bf16x8*)&Bs[(wn0 + nt * 16 + lr) * 40 + lg * 8];
#pragma unroll
    for (int mt = 0; mt < 4; mt++)
#pragma unroll
      for (int nt = 0; nt < 2; nt++)
        acc[mt][nt] = __builtin_amdgcn_mfma_f32_16x16x32_bf16(af[mt], bfr[nt], acc[mt][nt], 0, 0, 0);
  }
  float bv[2];
#pragma unroll
  for (int nt = 0; nt < 2; nt++)
    bv[nt] = BIAS ? bias[n0 + wn0 + nt * 16 + lr] : 0.f;
#pragma unroll
  for (int mt = 0; mt < 4; mt++)
#pragma unroll
    for (int nt = 0; nt < 2; nt++)
#pragma unroll
      for (int r = 0; r < 4; r++) {
        int row = m0 + wm0 + mt * 16 + lg * 4 + r;
        int col = n0 + wn0 + nt * 16 + lr;
        C[(size_t)row * N + col] = acc[mt][nt][r] + bv[nt];
      }
}

// ---------------- qkv fp32 -> head-major bf16 Q (l2norm*SCALE), K (l2norm) -------
// Layout: Qb/Kb[(b*8+h)*1024 + n][32]
__global__ void cvt_qkv_k(const float* __restrict__ qkv,
                          unsigned short* __restrict__ Qb,
                          unsigned short* __restrict__ Kb) {
  int n = blockIdx.x;              // 0..8191
  int t = threadIdx.x;             // 0..127
  int b = n >> 10, nr = n & 1023;
  int sec = t >> 6, lane = t & 63;
  const float* p = qkv + (size_t)n * QKVN + sec * 256 + lane * 4;
  float4 v = *(const float4*)p;
  float s = v.x * v.x + v.y * v.y + v.z * v.z + v.w * v.w;
  s += __shfl_xor(s, 1, 64); s += __shfl_xor(s, 2, 64); s += __shfl_xor(s, 4, 64);
  float inv = 1.f / fmaxf(sqrtf(s), 1e-12f);
  if (sec == 0) inv *= 0.17677669529663687f;   // fold softmax scale into q
  int h = lane >> 3, d4 = (lane & 7) << 2;
  unsigned short* dst = (sec == 0 ? Qb : Kb) + ((size_t)((b * 8 + h) * 1024 + nr)) * 32 + d4;
  us4 o = {f2bf(v.x * inv), f2bf(v.y * inv), f2bf(v.z * inv), f2bf(v.w * inv)};
  *(us4*)dst = o;
}

// ---------------- v cols of qkv -> transposed bf16 V^T [bh][d][1024] -------------
// Block: (token-tile tt of 64, bh). LDS 32 d-rows x 64 tokens, stride VPAD=66
// shorts (r10 bug: stride 34 < 64 made rows overlap + overran the buffer).
// Write banks: d8 groups at dword offset 8*d8/8*... = {0,8,16,24} disjoint
// (66*8/2=264 ≡ 8 mod 32); within group 2-lane b16 pairing = free.
#define VPAD 66
__global__ __launch_bounds__(256) void vT_k(const float* __restrict__ qkv,
                                            unsigned short* __restrict__ Vt) {
  __shared__ unsigned short Vl[32 * VPAD];
  const int tt = blockIdx.x, bh = blockIdx.y;
  const int b = bh >> 3, h = bh & 7;
  const int n0 = tt * 64;
  const int t = threadIdx.x;
  {  // read 64 tokens x 32 d, cvt, store transposed to LDS
    int nl = t >> 2, d8 = (t & 3) * 8;
    const float* p = qkv + (size_t)(b * 1024 + n0 + nl) * QKVN + 512 + h * 32 + d8;
    float4 a = *(const float4*)p;
    float4 c = *(const float4*)(p + 4);
    float vv[8] = {a.x, a.y, a.z, a.w, c.x, c.y, c.z, c.w};
#pragma unroll
    for (int i = 0; i < 8; i++) Vl[(d8 + i) * VPAD + nl] = f2bf(vv[i]);
  }
  __syncthreads();
  {  // write out rows: 16 contiguous shorts per thread
    int d = t >> 3, seg = t & 7;
    us4 lo = *(const us4*)&Vl[d * VPAD + seg * 8];
    us4 hi = *(const us4*)&Vl[d * VPAD + seg * 8 + 4];
    unsigned short* dst = Vt + ((size_t)(bh * 32 + d) << 10) + n0 + seg * 8;
    *(us4*)dst = lo;
    *(us4*)(dst + 4) = hi;
  }
}

// ---------------- MFMA bf16 flash attention (no-max variant), barrier-free -------
// 1 wave = 32 q rows. K and V^T read directly from global (L2-hot: 32 blocks/bh).
// P bounced via wave-private LDS, stride 36 shorts (write banks lg*72 mod 32 =
// {0,8,16,24} disjoint; reads 2xb64 per frag, ~2-4 way).
#define PSTR 36

__global__ __launch_bounds__(64) void attn_mfma_k(const unsigned short* __restrict__ Qb,
                                                  const unsigned short* __restrict__ Kb,
                                                  const unsigned short* __restrict__ Vt,
                                                  unsigned short* __restrict__ obuf) {
  __shared__ __align__(16) unsigned short Pl[32 * PSTR];
  const int bh = blockIdx.y;
  const int q0 = blockIdx.x * 32;
  const int lane = threadIdx.x;
  const int lg = lane >> 4, lr = lane & 15;
  const size_t base = (size_t)bh * NTOK;
  const unsigned short* vb = Vt + ((size_t)bh * 32 << 10);

  bf16x8 qf[2];
#pragma unroll
  for (int qt = 0; qt < 2; qt++)
    qf[qt] = *(const bf16x8*)(Qb + (base + q0 + qt * 16 + lr) * 32 + lg * 8);

  f32x4 o[2][2] = {};        // rows q=16qt+4lg+r, cols d=16dt+lr
  float lpart[2][4] = {};

  for (int step = 0; step < 32; step++) {
    const int kv0 = step * 32;
    bf16x8 kf[2];
#pragma unroll
    for (int ct = 0; ct < 2; ct++)
      kf[ct] = *(const bf16x8*)(Kb + (base + kv0 + ct * 16 + lr) * 32 + lg * 8);
#pragma unroll
    for (int qt = 0; qt < 2; qt++) {
#pragma unroll
      for (int ct = 0; ct < 2; ct++) {
        f32x4 c = {};
        c = __builtin_amdgcn_mfma_f32_16x16x32_bf16(qf[qt], kf[ct], c, 0, 0, 0);
#pragma unroll
        for (int r = 0; r < 4; r++) {
          float p = __expf(c[r]);
          lpart[qt][r] += p;
          Pl[(qt * 16 + lg * 4 + r) * PSTR + ct * 16 + lr] = f2bf(p);
        }
      }
    }
#pragma unroll
    for (int qt = 0; qt < 2; qt++) {
      us4 plo = *(const us4*)&Pl[(qt * 16 + lr) * PSTR + lg * 8];
      us4 phi = *(const us4*)&Pl[(qt * 16 + lr) * PSTR + lg * 8 + 4];
      bf16x8 pf = {(short)plo[0], (short)plo[1], (short)plo[2], (short)plo[3],
                   (short)phi[0], (short)phi[1], (short)phi[2], (short)phi[3]};
#pragma unroll
      for (int dt = 0; dt < 2; dt++) {
        bf16x8 vf = *(const bf16x8*)(vb + ((size_t)(dt * 16 + lr) << 10) + kv0 + lg * 8);
        o[qt][dt] = __builtin_amdgcn_mfma_f32_16x16x32_bf16(pf, vf, o[qt][dt], 0, 0, 0);
      }
    }
  }
#pragma unroll
  for (int qt = 0; qt < 2; qt++) {
#pragma unroll
    for (int r = 0; r < 4; r++) {
      float l = lpart[qt][r];
      l += __shfl_xor(l, 1, 64); l += __shfl_xor(l, 2, 64);
      l += __shfl_xor(l, 4, 64); l += __shfl_xor(l, 8, 64);
      lpart[qt][r] = 1.f / l;
    }
  }
  const int b = bh >> 3, h = bh & 7;
#pragma unroll
  for (int qt = 0; qt < 2; qt++)
#pragma unroll
    for (int dt = 0; dt < 2; dt++)
#pragma unroll
      for (int r = 0; r < 4; r++) {
        int q = q0 + qt * 16 + lg * 4 + r;
        int c = h * 32 + dt * 16 + lr;
        obuf[((size_t)(b * NTOK + q)) * DIMC + c] = f2bf(o[qt][dt][r] * lpart[qt][r]);
      }
}

// ---------------- per-row (channel) LayerNorm + GELU, one row per wave ------------
template <bool OBF>
__global__ void ln_gelu_k(const float* __restrict__ in, const float* __restrict__ g,
                          const float* __restrict__ bb, void* __restrict__ outv) {
  int t = threadIdx.x;
  int lane = t & 63;
  int r = blockIdx.x * 4 + (t >> 6);
  const float* p = in + ((size_t)r << 8) + (lane << 2);
  float4 v = *(const float4*)p;
  float s1 = v.x + v.y + v.z + v.w;
  float s2 = v.x * v.x + v.y * v.y + v.z * v.z + v.w * v.w;
#pragma unroll
  for (int m = 1; m < 64; m <<= 1) {
    s1 += __shfl_xor(s1, m, 64);
    s2 += __shfl_xor(s2, m, 64);
  }
  float mu = s1 * (1.f / 256.f);
  float var = s2 * (1.f / 256.f) - mu * mu;
  float rstd = rsqrtf(var + 1e-5f);
  float4 gv = *(const float4*)(g + (lane << 2));
  float4 bv = *(const float4*)(bb + (lane << 2));
  float4 ov;
  ov.x = gelu_f((v.x - mu) * rstd * gv.x + bv.x);
  ov.y = gelu_f((v.y - mu) * rstd * gv.y + bv.y);
  ov.z = gelu_f((v.z - mu) * rstd * gv.z + bv.z);
  ov.w = gelu_f((v.w - mu) * rstd * gv.w + bv.w);
  if (OBF) {
    us4 ob = {f2bf(ov.x), f2bf(ov.y), f2bf(ov.z), f2bf(ov.w)};
    *(us4*)((unsigned short*)outv + ((size_t)r << 8) + (lane << 2)) = ob;
  } else {
    *(float4*)((float*)outv + ((size_t)r << 8) + (lane << 2)) = ov;
  }
}

// ---------------- [B,HW,C] -> NCHW transpose + identity add ----------------------
__global__ void trans_add_k(const float* __restrict__ m2, const float* __restrict__ x,
                            float* __restrict__ out) {
  __shared__ float tile[32][33];
  int b = blockIdx.z, c0 = blockIdx.y << 5, s0 = blockIdx.x << 5;
  int t = threadIdx.x;
  int j = t & 31, i0 = t >> 5;
#pragma unroll
  for (int i = i0; i < 32; i += 8)
    tile[i][j] = m2[(size_t)(b * 1024 + s0 + i) * 256 + c0 + j];
  __syncthreads();
#pragma unroll
  for (int i2 = i0; i2 < 32; i2 += 8) {
    size_t idx = ((size_t)(b * 256 + c0 + i2) << 10) + s0 + j;
    out[idx] = x[idx] + tile[j][i2];
  }
}

extern "C" void kernel_launch(void* const* d_in, const int* in_sizes, int n_in,
                              void* d_out, int out_size, void* d_ws, size_t ws_size,
                              hipStream_t stream) {
  const float* x     = (const float*)d_in[0];
  const float* dw_w  = (const float*)d_in[1];
  const float* dw_b  = (const float*)d_in[2];
  const float* qkv_w = (const float*)d_in[3];
  const float* c1_w  = (const float*)d_in[4];
  const float* c1_b  = (const float*)d_in[5];
  const float* ln1_g = (const float*)d_in[6];
  const float* ln1_b = (const float*)d_in[7];
  const float* c2_w  = (const float*)d_in[8];
  const float* c2_b  = (const float*)d_in[9];
  const float* ln2_g = (const float*)d_in[10];
  const float* ln2_b = (const float*)d_in[11];
  float* out = (float*)d_out;

  float* ws = (float*)d_ws;
  const size_t MF = (size_t)1 << 20;   // 1M floats = 4 MB
  // Layout (disjoint-while-live; peak 13 MF = 52 MB <= 53 MB proven):
  //   y2 [0,2M) dead after t2b | A0 [2M,3M) dead after qkv-gemm | Wb [3M,3.25M)
  //   qkv [4M,10M) dead after vT_k | Qb [10M,11M) Kb [11M,12M) Vt [12M,13M)
  //   obuf bf16 [0,1M) | m1 bf16 [1M,2M) | buf1 [4M,6M) | buf2 [6M,8M) | m2b [8M,10M)
  float* y2   = ws;
  unsigned short* A0 = (unsigned short*)(ws + 2 * MF);
  unsigned short* Wb = (unsigned short*)(ws + 3 * MF);
  float* qkv  = ws + 4 * MF;
  unsigned short* Qb = (unsigned short*)(ws + 10 * MF);
  unsigned short* Kb = (unsigned short*)(ws + 11 * MF);
  unsigned short* Vtb = (unsigned short*)(ws + 12 * MF);
  unsigned short* obuf = (unsigned short*)ws;
  unsigned short* m1 = (unsigned short*)(ws + 1 * MF);
  float* buf1 = ws + 4 * MF;
  float* buf2 = ws + 6 * MF;
  float* m2b  = ws + 8 * MF;
  (void)in_sizes; (void)n_in; (void)out_size; (void)ws_size;

  dwconv_k<<<2048, 256, 0, stream>>>(x, dw_w, dw_b, y2);
  cvt_w_k<<<320, 256, 0, stream>>>(qkv_w, c1_w, c2_w, Wb);
  t2b_k<<<dim3(32, 8, 8), 256, 0, stream>>>(y2, A0);
  mgemm_k<false><<<dim3(12, 64), 256, 0, stream>>>(A0, Wb, nullptr, qkv, 768);
  cvt_qkv_k<<<8192, 128, 0, stream>>>(qkv, Qb, Kb);
  vT_k<<<dim3(16, 64), 256, 0, stream>>>(qkv, Vtb);
  attn_mfma_k<<<dim3(32, 64), 64, 0, stream>>>(Qb, Kb, Vtb, obuf);
  mgemm_k<true><<<dim3(4, 64), 256, 0, stream>>>(obuf, Wb + 196608, c1_b, buf1, 256);
  ln_gelu_k<true><<<2048, 256, 0, stream>>>(buf1, ln1_g, ln1_b, m1);
  mgemm_k<true><<<dim3(4, 64), 256, 0, stream>>>(m1, Wb + 262144, c2_b, buf2, 256);
  ln_gelu_k<false><<<2048, 256, 0, stream>>>(buf2, ln2_g, ln2_b, m2b);
  trans_add_k<<<dim3(32, 8, 8), 256, 0, stream>>>(m2b, x, out);
}

// Round 13
// 169.540 us; speedup vs baseline: 2.5871x; 1.0514x over previous
//
#include <hip/hip_runtime.h>
#include <math.h>

#define DIMC 256
#define NTOK 1024   // H*W
#define QKVN 768
#define HDIM 32

typedef __attribute__((ext_vector_type(8))) short bf16x8;
typedef __attribute__((ext_vector_type(4))) float f32x4;
typedef __attribute__((ext_vector_type(4))) unsigned short us4;

__device__ __forceinline__ unsigned short f2bf(float f) {
  unsigned u = __float_as_uint(f);
  u += 0x7FFF + ((u >> 16) & 1);          // round-to-nearest-even
  return (unsigned short)(u >> 16);
}

__device__ __forceinline__ float gelu_f(float y) {
  return 0.5f * y * (1.f + erff(y * 0.70710678118654752f));
}

// ---- fused: depthwise 3x3 -> A0 [B][HW][C] bf16  (+ weight cvt in tail blocks) --
// Conv blocks (0..2047): b = blk>>8, h-row = (blk>>3)&31, c-tile = (blk&7)*32.
// Stage x rows h-1..h+1 for 32 channels in LDS, compute, write token-major bf16.
__global__ __launch_bounds__(256) void dwt_k(const float* __restrict__ x,
                                             const float* __restrict__ w,
                                             const float* __restrict__ b,
                                             unsigned short* __restrict__ A0,
                                             const float* __restrict__ w0,
                                             const float* __restrict__ w1,
                                             const float* __restrict__ w2,
                                             unsigned short* __restrict__ Wb) {
  int blk = blockIdx.x;
  int t = threadIdx.x;
  if (blk >= 2048) {                      // weight fp32->bf16: 327680 elems
    int i = ((blk - 2048) * 256 + t) * 4;
    const float* src;
    int off;
    if (i < 196608) { src = w0; off = i; }
    else if (i < 262144) { src = w1; off = i - 196608; }
    else { src = w2; off = i - 262144; }
    float4 v = *(const float4*)(src + off);
    us4 o = {f2bf(v.x), f2bf(v.y), f2bf(v.z), f2bf(v.w)};
    *(us4*)(Wb + i) = o;
    return;
  }
  __shared__ float xs[32][3][33];         // [c][dh][w]
  __shared__ float ws9[32][9];
  __shared__ float bs[32];
  const int b_ = blk >> 8, h = (blk >> 3) & 31, c0 = (blk & 7) << 5;
  {  // load 3 rows x 32 channels (zero-pad out-of-range rows)
    int cl = t >> 3, seg = (t & 7) << 2;
    const float* xp = x + ((size_t)(b_ * 256 + c0 + cl) << 10);
#pragma unroll
    for (int dh = 0; dh < 3; dh++) {
      int h2 = h + dh - 1;
      float4 v = {0.f, 0.f, 0.f, 0.f};
      if ((unsigned)h2 < 32u) v = *(const float4*)(xp + h2 * 32 + seg);
      xs[cl][dh][seg + 0] = v.x; xs[cl][dh][seg + 1] = v.y;
      xs[cl][dh][seg + 2] = v.z; xs[cl][dh][seg + 3] = v.w;
    }
  }
  for (int i = t; i < 288; i += 256) ws9[i / 9][i % 9] = w[(c0 + i / 9) * 9 + i % 9];
  if (t < 32) bs[t] = b[c0 + t];
  __syncthreads();
  const int wp = t >> 3, cq = (t & 7) << 2;   // token col wp, channels cq..cq+3
  us4 o;
#pragma unroll
  for (int j = 0; j < 4; j++) {
    int c = cq + j;
    float acc = bs[c];
#pragma unroll
    for (int dh = 0; dh < 3; dh++) {
#pragma unroll
      for (int dw = 0; dw < 3; dw++) {
        int w2 = wp + dw - 1;
        if ((unsigned)w2 < 32u) acc += xs[c][dh][w2] * ws9[c][dh * 3 + dw];
      }
    }
    o[j] = f2bf(acc);
  }
  *(us4*)(A0 + (((size_t)(b_ * 1024 + h * 32 + wp)) << 8) + c0 + cq) = o;
}

// ---------------- bf16 MFMA GEMM: C[M,N] = A[M,256] * W[N,256]^T (+bias) ---------
template <bool BIAS>
__global__ __launch_bounds__(256) void mgemm_k(const unsigned short* __restrict__ A,
                                               const unsigned short* __restrict__ W,
                                               const float* __restrict__ bias,
                                               float* __restrict__ C, int N) {
  __shared__ __align__(16) unsigned short As[128 * 40];
  __shared__ __align__(16) unsigned short Bs[64 * 40];
  const int t = threadIdx.x;
  const int m0 = blockIdx.y * 128;
  const int n0 = blockIdx.x * 64;
  const int wid = t >> 6, lane = t & 63;
  const int lg = lane >> 4, lr = lane & 15;
  const int wm0 = (wid >> 1) * 64, wn0 = (wid & 1) * 32;

  f32x4 acc[4][2] = {};
  for (int k0 = 0; k0 < 256; k0 += 32) {
    __syncthreads();
    {
#pragma unroll
      for (int u = 0; u < 2; u++) {
        int f = t + u * 256;
        int r = f >> 2, c = f & 3;
        bf16x8 v = *(const bf16x8*)(A + (size_t)(m0 + r) * 256 + k0 + c * 8);
        *(bf16x8*)&As[r * 40 + c * 8] = v;
      }
      int o = t >> 2, c = t & 3;
      bf16x8 v = *(const bf16x8*)(W + (size_t)(n0 + o) * 256 + k0 + c * 8);
      *(bf16x8*)&Bs[o * 40 + c * 8] = v;
    }
    __syncthreads();
    bf16x8 af[4], bfr[2];
#pragma unroll
    for (int mt = 0; mt < 4; mt++)
      af[mt] = *(const bf16x8*)&As[(wm0 + mt * 16 + lr) * 40 + lg * 8];
#pragma unroll
    for (int nt = 0; nt < 2; nt++)
      bfr[nt] = *(const bf16x8*)&Bs[(wn0 + nt * 16 + lr) * 40 + lg * 8];
#pragma unroll
    for (int mt = 0; mt < 4; mt++)
#pragma unroll
      for (int nt = 0; nt < 2; nt++)
        acc[mt][nt] = __builtin_amdgcn_mfma_f32_16x16x32_bf16(af[mt], bfr[nt], acc[mt][nt], 0, 0, 0);
  }
  float bv[2];
#pragma unroll
  for (int nt = 0; nt < 2; nt++)
    bv[nt] = BIAS ? bias[n0 + wn0 + nt * 16 + lr] : 0.f;
#pragma unroll
  for (int mt = 0; mt < 4; mt++)
#pragma unroll
    for (int nt = 0; nt < 2; nt++)
#pragma unroll
      for (int r = 0; r < 4; r++) {
        int row = m0 + wm0 + mt * 16 + lg * 4 + r;
        int col = n0 + wn0 + nt * 16 + lr;
        C[(size_t)row * N + col] = acc[mt][nt][r] + bv[nt];
      }
}

// ---- fused qkv prep: q,k l2norm->bf16 head-major + v -> transposed V^T ----------
// Grid (16 token-tiles, 64 bh). q/k: 2 lanes per token (16 ch each), xor-1 norm.
// v: LDS transpose, stride VPAD=66 (rows disjoint, bank groups {0,8,16,24}).
#define VPAD 66
__global__ __launch_bounds__(256) void qkvprep_k(const float* __restrict__ qkv,
                                                 unsigned short* __restrict__ Qb,
                                                 unsigned short* __restrict__ Kb,
                                                 unsigned short* __restrict__ Vt) {
  __shared__ unsigned short Vl[32 * VPAD];
  const int tt = blockIdx.x, bh = blockIdx.y;
  const int b = bh >> 3, h = bh & 7;
  const int n0 = tt * 64;
  const int t = threadIdx.x;
  {  // q (waves 0-1) / k (waves 2-3): token nl, 16-ch half e0
    int pair = t >> 7, idx = t & 127;
    int nl = idx >> 1, e0 = (idx & 1) << 4;
    const float* p = qkv + (size_t)(b * 1024 + n0 + nl) * QKVN + pair * 256 + h * 32 + e0;
    float4 v0 = *(const float4*)(p + 0);
    float4 v1 = *(const float4*)(p + 4);
    float4 v2 = *(const float4*)(p + 8);
    float4 v3 = *(const float4*)(p + 12);
    float s = v0.x * v0.x + v0.y * v0.y + v0.z * v0.z + v0.w * v0.w
            + v1.x * v1.x + v1.y * v1.y + v1.z * v1.z + v1.w * v1.w
            + v2.x * v2.x + v2.y * v2.y + v2.z * v2.z + v2.w * v2.w
            + v3.x * v3.x + v3.y * v3.y + v3.z * v3.z + v3.w * v3.w;
    s += __shfl_xor(s, 1, 64);
    float inv = 1.f / fmaxf(sqrtf(s), 1e-12f);
    if (pair == 0) inv *= 0.17677669529663687f;    // fold softmax scale into q
    unsigned short* dst = (pair ? Kb : Qb) + ((size_t)(bh * 1024 + n0 + nl)) * 32 + e0;
    us4 o0 = {f2bf(v0.x * inv), f2bf(v0.y * inv), f2bf(v0.z * inv), f2bf(v0.w * inv)};
    us4 o1 = {f2bf(v1.x * inv), f2bf(v1.y * inv), f2bf(v1.z * inv), f2bf(v1.w * inv)};
    us4 o2 = {f2bf(v2.x * inv), f2bf(v2.y * inv), f2bf(v2.z * inv), f2bf(v2.w * inv)};
    us4 o3 = {f2bf(v3.x * inv), f2bf(v3.y * inv), f2bf(v3.z * inv), f2bf(v3.w * inv)};
    *(us4*)(dst + 0) = o0; *(us4*)(dst + 4) = o1;
    *(us4*)(dst + 8) = o2; *(us4*)(dst + 12) = o3;
  }
  {  // v: read 64 tokens x 32 d, cvt, transpose to LDS
    int nl = t >> 2, d8 = (t & 3) * 8;
    const float* p = qkv + (size_t)(b * 1024 + n0 + nl) * QKVN + 512 + h * 32 + d8;
    float4 a = *(const float4*)p;
    float4 c = *(const float4*)(p + 4);
    float vv[8] = {a.x, a.y, a.z, a.w, c.x, c.y, c.z, c.w};
#pragma unroll
    for (int i = 0; i < 8; i++) Vl[(d8 + i) * VPAD + nl] = f2bf(vv[i]);
  }
  __syncthreads();
  {  // write V^T rows: 16 contiguous shorts per thread
    int d = t >> 3, seg = t & 7;
    us4 lo = *(const us4*)&Vl[d * VPAD + seg * 8];
    us4 hi = *(const us4*)&Vl[d * VPAD + seg * 8 + 4];
    unsigned short* dst = Vt + ((size_t)(bh * 32 + d) << 10) + n0 + seg * 8;
    *(us4*)dst = lo;
    *(us4*)(dst + 4) = hi;
  }
}

// ---------------- MFMA bf16 flash attention (no-max variant), barrier-free -------
#define PSTR 36

__global__ __launch_bounds__(64) void attn_mfma_k(const unsigned short* __restrict__ Qb,
                                                  const unsigned short* __restrict__ Kb,
                                                  const unsigned short* __restrict__ Vt,
                                                  unsigned short* __restrict__ obuf) {
  __shared__ __align__(16) unsigned short Pl[32 * PSTR];
  const int bh = blockIdx.y;
  const int q0 = blockIdx.x * 32;
  const int lane = threadIdx.x;
  const int lg = lane >> 4, lr = lane & 15;
  const size_t base = (size_t)bh * NTOK;
  const unsigned short* vb = Vt + ((size_t)bh * 32 << 10);

  bf16x8 qf[2];
#pragma unroll
  for (int qt = 0; qt < 2; qt++)
    qf[qt] = *(const bf16x8*)(Qb + (base + q0 + qt * 16 + lr) * 32 + lg * 8);

  f32x4 o[2][2] = {};
  float lpart[2][4] = {};

  for (int step = 0; step < 32; step++) {
    const int kv0 = step * 32;
    bf16x8 kf[2];
#pragma unroll
    for (int ct = 0; ct < 2; ct++)
      kf[ct] = *(const bf16x8*)(Kb + (base + kv0 + ct * 16 + lr) * 32 + lg * 8);
#pragma unroll
    for (int qt = 0; qt < 2; qt++) {
#pragma unroll
      for (int ct = 0; ct < 2; ct++) {
        f32x4 c = {};
        c = __builtin_amdgcn_mfma_f32_16x16x32_bf16(qf[qt], kf[ct], c, 0, 0, 0);
#pragma unroll
        for (int r = 0; r < 4; r++) {
          float p = __expf(c[r]);
          lpart[qt][r] += p;
          Pl[(qt * 16 + lg * 4 + r) * PSTR + ct * 16 + lr] = f2bf(p);
        }
      }
    }
#pragma unroll
    for (int qt = 0; qt < 2; qt++) {
      us4 plo = *(const us4*)&Pl[(qt * 16 + lr) * PSTR + lg * 8];
      us4 phi = *(const us4*)&Pl[(qt * 16 + lr) * PSTR + lg * 8 + 4];
      bf16x8 pf = {(short)plo[0], (short)plo[1], (short)plo[2], (short)plo[3],
                   (short)phi[0], (short)phi[1], (short)phi[2], (short)phi[3]};
#pragma unroll
      for (int dt = 0; dt < 2; dt++) {
        bf16x8 vf = *(const bf16x8*)(vb + ((size_t)(dt * 16 + lr) << 10) + kv0 + lg * 8);
        o[qt][dt] = __builtin_amdgcn_mfma_f32_16x16x32_bf16(pf, vf, o[qt][dt], 0, 0, 0);
      }
    }
  }
#pragma unroll
  for (int qt = 0; qt < 2; qt++) {
#pragma unroll
    for (int r = 0; r < 4; r++) {
      float l = lpart[qt][r];
      l += __shfl_xor(l, 1, 64); l += __shfl_xor(l, 2, 64);
      l += __shfl_xor(l, 4, 64); l += __shfl_xor(l, 8, 64);
      lpart[qt][r] = 1.f / l;
    }
  }
  const int b = bh >> 3, h = bh & 7;
#pragma unroll
  for (int qt = 0; qt < 2; qt++)
#pragma unroll
    for (int dt = 0; dt < 2; dt++)
#pragma unroll
      for (int r = 0; r < 4; r++) {
        int q = q0 + qt * 16 + lg * 4 + r;
        int c = h * 32 + dt * 16 + lr;
        obuf[((size_t)(b * NTOK + q)) * DIMC + c] = f2bf(o[qt][dt][r] * lpart[qt][r]);
      }
}

// ---------------- per-row LayerNorm + GELU, one row per wave, bf16 out -----------
__global__ void ln_gelu_k(const float* __restrict__ in, const float* __restrict__ g,
                          const float* __restrict__ bb, unsigned short* __restrict__ out) {
  int t = threadIdx.x;
  int lane = t & 63;
  int r = blockIdx.x * 4 + (t >> 6);
  const float* p = in + ((size_t)r << 8) + (lane << 2);
  float4 v = *(const float4*)p;
  float s1 = v.x + v.y + v.z + v.w;
  float s2 = v.x * v.x + v.y * v.y + v.z * v.z + v.w * v.w;
#pragma unroll
  for (int m = 1; m < 64; m <<= 1) {
    s1 += __shfl_xor(s1, m, 64);
    s2 += __shfl_xor(s2, m, 64);
  }
  float mu = s1 * (1.f / 256.f);
  float var = s2 * (1.f / 256.f) - mu * mu;
  float rstd = rsqrtf(var + 1e-5f);
  float4 gv = *(const float4*)(g + (lane << 2));
  float4 bv = *(const float4*)(bb + (lane << 2));
  us4 ob = {f2bf(gelu_f((v.x - mu) * rstd * gv.x + bv.x)),
            f2bf(gelu_f((v.y - mu) * rstd * gv.y + bv.y)),
            f2bf(gelu_f((v.z - mu) * rstd * gv.z + bv.z)),
            f2bf(gelu_f((v.w - mu) * rstd * gv.w + bv.w))};
  *(us4*)(out + ((size_t)r << 8) + (lane << 2)) = ob;
}

// ---- fused: LayerNorm + GELU + [B,HW,C]->NCHW transpose + identity add ----------
// Grid (32 hw-tiles, 8 b). LDS [32][257]: read banks j*257+c -> j (conflict-free).
__global__ __launch_bounds__(256) void ln_trans_k(const float* __restrict__ in,
                                                  const float* __restrict__ g,
                                                  const float* __restrict__ bb,
                                                  const float* __restrict__ x,
                                                  float* __restrict__ out) {
  __shared__ float ys[32][257];
  const int b = blockIdx.y, s0 = blockIdx.x << 5;
  const int t = threadIdx.x, lane = t & 63, wv = t >> 6;
  float gv[4], bv[4];
#pragma unroll
  for (int e = 0; e < 4; e++) { gv[e] = g[lane + 64 * e]; bv[e] = bb[lane + 64 * e]; }
  for (int i = 0; i < 8; i++) {
    int tok = wv * 8 + i;
    size_t r = (size_t)(b * 1024 + s0 + tok) << 8;
    float v[4];
    float s1 = 0.f, s2 = 0.f;
#pragma unroll
    for (int e = 0; e < 4; e++) {
      v[e] = in[r + lane + 64 * e];
      s1 += v[e]; s2 += v[e] * v[e];
    }
#pragma unroll
    for (int m = 1; m < 64; m <<= 1) {
      s1 += __shfl_xor(s1, m, 64);
      s2 += __shfl_xor(s2, m, 64);
    }
    float mu = s1 * (1.f / 256.f);
    float var = s2 * (1.f / 256.f) - mu * mu;
    float rstd = rsqrtf(var + 1e-5f);
#pragma unroll
    for (int e = 0; e < 4; e++)
      ys[tok][lane + 64 * e] = gelu_f((v[e] - mu) * rstd * gv[e] + bv[e]);
  }
  __syncthreads();
  const int j = t & 31, cr = t >> 5;
  for (int c = cr; c < 256; c += 8) {
    size_t idx = ((size_t)(b * 256 + c) << 10) + s0 + j;
    out[idx] = x[idx] + ys[j][c];
  }
}

extern "C" void kernel_launch(void* const* d_in, const int* in_sizes, int n_in,
                              void* d_out, int out_size, void* d_ws, size_t ws_size,
                              hipStream_t stream) {
  const float* x     = (const float*)d_in[0];
  const float* dw_w  = (const float*)d_in[1];
  const float* dw_b  = (const float*)d_in[2];
  const float* qkv_w = (const float*)d_in[3];
  const float* c1_w  = (const float*)d_in[4];
  const float* c1_b  = (const float*)d_in[5];
  const float* ln1_g = (const float*)d_in[6];
  const float* ln1_b = (const float*)d_in[7];
  const float* c2_w  = (const float*)d_in[8];
  const float* c2_b  = (const float*)d_in[9];
  const float* ln2_g = (const float*)d_in[10];
  const float* ln2_b = (const float*)d_in[11];
  float* out = (float*)d_out;

  float* ws = (float*)d_ws;
  const size_t MF = (size_t)1 << 20;   // 1M floats = 4 MB
  // Lifetimes (peak 11 MF = 44 MB < 52 proven-safe):
  //   Wb [0,0.25M) lives to end (0.65 MB used of 1 MB slot)
  //   A0 [0.25M,1.25M) bf16, dead after qkv-gemm
  //   qkv [2M,8M) dead after qkvprep | Qb [8,9) Kb [9,10) Vt [10,11) dead after attn
  //   obuf bf16 [0.25M,1.25M) reuse A0 | buf1 [2M,4M) reuse qkv | m1 bf16 [4M,5M)
  //   buf2 [5M,7M)
  unsigned short* Wb = (unsigned short*)ws;
  unsigned short* A0 = (unsigned short*)(ws + MF / 4);
  float* qkv  = ws + 2 * MF;
  unsigned short* Qb = (unsigned short*)(ws + 8 * MF);
  unsigned short* Kb = (unsigned short*)(ws + 9 * MF);
  unsigned short* Vtb = (unsigned short*)(ws + 10 * MF);
  unsigned short* obuf = (unsigned short*)(ws + MF / 4);
  float* buf1 = ws + 2 * MF;
  unsigned short* m1 = (unsigned short*)(ws + 4 * MF);
  float* buf2 = ws + 5 * MF;
  (void)in_sizes; (void)n_in; (void)out_size; (void)ws_size;

  dwt_k<<<2368, 256, 0, stream>>>(x, dw_w, dw_b, A0, qkv_w, c1_w, c2_w, Wb);
  mgemm_k<false><<<dim3(12, 64), 256, 0, stream>>>(A0, Wb, nullptr, qkv, 768);
  qkvprep_k<<<dim3(16, 64), 256, 0, stream>>>(qkv, Qb, Kb, Vtb);
  attn_mfma_k<<<dim3(32, 64), 64, 0, stream>>>(Qb, Kb, Vtb, obuf);
  mgemm_k<true><<<dim3(4, 64), 256, 0, stream>>>(obuf, Wb + 196608, c1_b, buf1, 256);
  ln_gelu_k<<<2048, 256, 0, stream>>>(buf1, ln1_g, ln1_b, m1);
  mgemm_k<true><<<dim3(4, 64), 256, 0, stream>>>(m1, Wb + 262144, c2_b, buf2, 256);
  ln_trans_k<<<dim3(32, 8), 256, 0, stream>>>(buf2, ln2_g, ln2_b, x, out);
}

// Round 14
// 161.479 us; speedup vs baseline: 2.7163x; 1.0499x over previous
//
#include <hip/hip_runtime.h>
#include <math.h>

#define DIMC 256
#define NTOK 1024   // H*W
#define QKVN 768
#define HDIM 32

typedef __attribute__((ext_vector_type(8))) short bf16x8;
typedef __attribute__((ext_vector_type(4))) float f32x4;
typedef __attribute__((ext_vector_type(4))) unsigned short us4;

__device__ __forceinline__ unsigned short f2bf(float f) {
  unsigned u = __float_as_uint(f);
  u += 0x7FFF + ((u >> 16) & 1);          // round-to-nearest-even
  return (unsigned short)(u >> 16);
}

__device__ __forceinline__ float gelu_f(float y) {
  return 0.5f * y * (1.f + erff(y * 0.70710678118654752f));
}

// ---- fused: depthwise 3x3 -> A0 [B][HW][C] bf16  (+ weight cvt in tail blocks) --
__global__ __launch_bounds__(256) void dwt_k(const float* __restrict__ x,
                                             const float* __restrict__ w,
                                             const float* __restrict__ b,
                                             unsigned short* __restrict__ A0,
                                             const float* __restrict__ w0,
                                             const float* __restrict__ w1,
                                             const float* __restrict__ w2,
                                             unsigned short* __restrict__ Wb) {
  int blk = blockIdx.x;
  int t = threadIdx.x;
  if (blk >= 2048) {                      // weight fp32->bf16: 327680 elems
    int i = ((blk - 2048) * 256 + t) * 4;
    const float* src;
    int off;
    if (i < 196608) { src = w0; off = i; }
    else if (i < 262144) { src = w1; off = i - 196608; }
    else { src = w2; off = i - 262144; }
    float4 v = *(const float4*)(src + off);
    us4 o = {f2bf(v.x), f2bf(v.y), f2bf(v.z), f2bf(v.w)};
    *(us4*)(Wb + i) = o;
    return;
  }
  __shared__ float xs[32][3][33];         // [c][dh][w]
  __shared__ float ws9[32][9];
  __shared__ float bs[32];
  const int b_ = blk >> 8, h = (blk >> 3) & 31, c0 = (blk & 7) << 5;
  {
    int cl = t >> 3, seg = (t & 7) << 2;
    const float* xp = x + ((size_t)(b_ * 256 + c0 + cl) << 10);
#pragma unroll
    for (int dh = 0; dh < 3; dh++) {
      int h2 = h + dh - 1;
      float4 v = {0.f, 0.f, 0.f, 0.f};
      if ((unsigned)h2 < 32u) v = *(const float4*)(xp + h2 * 32 + seg);
      xs[cl][dh][seg + 0] = v.x; xs[cl][dh][seg + 1] = v.y;
      xs[cl][dh][seg + 2] = v.z; xs[cl][dh][seg + 3] = v.w;
    }
  }
  for (int i = t; i < 288; i += 256) ws9[i / 9][i % 9] = w[(c0 + i / 9) * 9 + i % 9];
  if (t < 32) bs[t] = b[c0 + t];
  __syncthreads();
  const int wp = t >> 3, cq = (t & 7) << 2;
  us4 o;
#pragma unroll
  for (int j = 0; j < 4; j++) {
    int c = cq + j;
    float acc = bs[c];
#pragma unroll
    for (int dh = 0; dh < 3; dh++) {
#pragma unroll
      for (int dw = 0; dw < 3; dw++) {
        int w2 = wp + dw - 1;
        if ((unsigned)w2 < 32u) acc += xs[c][dh][w2] * ws9[c][dh * 3 + dw];
      }
    }
    o[j] = f2bf(acc);
  }
  *(us4*)(A0 + (((size_t)(b_ * 1024 + h * 32 + wp)) << 8) + c0 + cq) = o;
}

// ---- qkv GEMM + fused l2norm/cvt epilogue -> Qb, Kb, Vt (no fp32 qkv buffer) ----
// Grid (x = 64 m-panels, y = 12 n-tiles): consecutive blocks share the W n-panel;
// per-XCD A-panel set repeats across y -> A0 L2-resident after first pass.
// BN=64: each wave's 32-col tile = exactly ONE head; block is purely q, k, or v.
__global__ __launch_bounds__(256) void mgemm_qkv_k(const unsigned short* __restrict__ A,
                                                   const unsigned short* __restrict__ W,
                                                   unsigned short* __restrict__ Qb,
                                                   unsigned short* __restrict__ Kb,
                                                   unsigned short* __restrict__ Vt) {
  __shared__ __align__(16) unsigned short As[128 * 40];
  __shared__ __align__(16) unsigned short Bs[64 * 40];
  const int t = threadIdx.x;
  const int m0 = blockIdx.x * 128;
  const int n0 = blockIdx.y * 64;
  const int wid = t >> 6, lane = t & 63;
  const int lg = lane >> 4, lr = lane & 15;
  const int wm0 = (wid >> 1) * 64, wn0 = (wid & 1) * 32;

  f32x4 acc[4][2] = {};
  for (int k0 = 0; k0 < 256; k0 += 32) {
    __syncthreads();
    {
#pragma unroll
      for (int u = 0; u < 2; u++) {
        int f = t + u * 256;
        int r = f >> 2, c = f & 3;
        bf16x8 v = *(const bf16x8*)(A + (size_t)(m0 + r) * 256 + k0 + c * 8);
        *(bf16x8*)&As[r * 40 + c * 8] = v;
      }
      int o = t >> 2, c = t & 3;
      bf16x8 v = *(const bf16x8*)(W + (size_t)(n0 + o) * 256 + k0 + c * 8);
      *(bf16x8*)&Bs[o * 40 + c * 8] = v;
    }
    __syncthreads();
    bf16x8 af[4], bfr[2];
#pragma unroll
    for (int mt = 0; mt < 4; mt++)
      af[mt] = *(const bf16x8*)&As[(wm0 + mt * 16 + lr) * 40 + lg * 8];
#pragma unroll
    for (int nt = 0; nt < 2; nt++)
      bfr[nt] = *(const bf16x8*)&Bs[(wn0 + nt * 16 + lr) * 40 + lg * 8];
#pragma unroll
    for (int mt = 0; mt < 4; mt++)
#pragma unroll
      for (int nt = 0; nt < 2; nt++)
        acc[mt][nt] = __builtin_amdgcn_mfma_f32_16x16x32_bf16(af[mt], bfr[nt], acc[mt][nt], 0, 0, 0);
  }
  // epilogue: this wave owns head h of section sec for 64 token-rows
  const int b_ = m0 >> 10;
  const int nr0 = (m0 & 1023) + wm0;
  const int sec = n0 >> 8;                         // 0=q 1=k 2=v
  const int h = ((n0 & 255) + wn0) >> 5;
  const int bh = b_ * 8 + h;
  if (sec < 2) {
    unsigned short* dst = (sec == 0 ? Qb : Kb);
    const float scl = (sec == 0) ? 0.17677669529663687f : 1.f;  // fold SCALE into q
#pragma unroll
    for (int mt = 0; mt < 4; mt++) {
#pragma unroll
      for (int r = 0; r < 4; r++) {
        float s = acc[mt][0][r] * acc[mt][0][r] + acc[mt][1][r] * acc[mt][1][r];
        s += __shfl_xor(s, 1, 64); s += __shfl_xor(s, 2, 64);
        s += __shfl_xor(s, 4, 64); s += __shfl_xor(s, 8, 64);   // sum over lr (head)
        float inv = scl / fmaxf(sqrtf(s), 1e-12f);
        int tok = nr0 + mt * 16 + lg * 4 + r;
        size_t rowoff = ((size_t)(bh << 10) + tok) * 32;
#pragma unroll
        for (int nt = 0; nt < 2; nt++)
          dst[rowoff + nt * 16 + lr] = f2bf(acc[mt][nt][r] * inv);
      }
    }
  } else {
#pragma unroll
    for (int mt = 0; mt < 4; mt++) {
      int tok0 = nr0 + mt * 16 + lg * 4;
#pragma unroll
      for (int nt = 0; nt < 2; nt++) {
        int d = nt * 16 + lr;
        us4 o = {f2bf(acc[mt][nt][0]), f2bf(acc[mt][nt][1]),
                 f2bf(acc[mt][nt][2]), f2bf(acc[mt][nt][3])};
        *(us4*)(Vt + (((size_t)(bh * 32 + d)) << 10) + tok0) = o;
      }
    }
  }
}

// ---------------- bf16 MFMA GEMM: C[M,N] = A[M,256] * W[N,256]^T (+bias) ---------
template <bool BIAS>
__global__ __launch_bounds__(256) void mgemm_k(const unsigned short* __restrict__ A,
                                               const unsigned short* __restrict__ W,
                                               const float* __restrict__ bias,
                                               float* __restrict__ C, int N) {
  __shared__ __align__(16) unsigned short As[128 * 40];
  __shared__ __align__(16) unsigned short Bs[64 * 40];
  const int t = threadIdx.x;
  const int m0 = blockIdx.y * 128;
  const int n0 = blockIdx.x * 64;
  const int wid = t >> 6, lane = t & 63;
  const int lg = lane >> 4, lr = lane & 15;
  const int wm0 = (wid >> 1) * 64, wn0 = (wid & 1) * 32;

  f32x4 acc[4][2] = {};
  for (int k0 = 0; k0 < 256; k0 += 32) {
    __syncthreads();
    {
#pragma unroll
      for (int u = 0; u < 2; u++) {
        int f = t + u * 256;
        int r = f >> 2, c = f & 3;
        bf16x8 v = *(const bf16x8*)(A + (size_t)(m0 + r) * 256 + k0 + c * 8);
        *(bf16x8*)&As[r * 40 + c * 8] = v;
      }
      int o = t >> 2, c = t & 3;
      bf16x8 v = *(const bf16x8*)(W + (size_t)(n0 + o) * 256 + k0 + c * 8);
      *(bf16x8*)&Bs[o * 40 + c * 8] = v;
    }
    __syncthreads();
    bf16x8 af[4], bfr[2];
#pragma unroll
    for (int mt = 0; mt < 4; mt++)
      af[mt] = *(const bf16x8*)&As[(wm0 + mt * 16 + lr) * 40 + lg * 8];
#pragma unroll
    for (int nt = 0; nt < 2; nt++)
      bfr[nt] = *(const bf16x8*)&Bs[(wn0 + nt * 16 + lr) * 40 + lg * 8];
#pragma unroll
    for (int mt = 0; mt < 4; mt++)
#pragma unroll
      for (int nt = 0; nt < 2; nt++)
        acc[mt][nt] = __builtin_amdgcn_mfma_f32_16x16x32_bf16(af[mt], bfr[nt], acc[mt][nt], 0, 0, 0);
  }
  float bv[2];
#pragma unroll
  for (int nt = 0; nt < 2; nt++)
    bv[nt] = BIAS ? bias[n0 + wn0 + nt * 16 + lr] : 0.f;
#pragma unroll
  for (int mt = 0; mt < 4; mt++)
#pragma unroll
    for (int nt = 0; nt < 2; nt++)
#pragma unroll
      for (int r = 0; r < 4; r++) {
        int row = m0 + wm0 + mt * 16 + lg * 4 + r;
        int col = n0 + wn0 + nt * 16 + lr;
        C[(size_t)row * N + col] = acc[mt][nt][r] + bv[nt];
      }
}

// ---------------- MFMA bf16 flash attention (no-max variant), barrier-free -------
#define PSTR 36

__global__ __launch_bounds__(64) void attn_mfma_k(const unsigned short* __restrict__ Qb,
                                                  const unsigned short* __restrict__ Kb,
                                                  const unsigned short* __restrict__ Vt,
                                                  unsigned short* __restrict__ obuf) {
  __shared__ __align__(16) unsigned short Pl[32 * PSTR];
  const int bh = blockIdx.y;
  const int q0 = blockIdx.x * 32;
  const int lane = threadIdx.x;
  const int lg = lane >> 4, lr = lane & 15;
  const size_t base = (size_t)bh * NTOK;
  const unsigned short* vb = Vt + ((size_t)bh * 32 << 10);

  bf16x8 qf[2];
#pragma unroll
  for (int qt = 0; qt < 2; qt++)
    qf[qt] = *(const bf16x8*)(Qb + (base + q0 + qt * 16 + lr) * 32 + lg * 8);

  f32x4 o[2][2] = {};
  float lpart[2][4] = {};

  for (int step = 0; step < 32; step++) {
    const int kv0 = step * 32;
    bf16x8 kf[2];
#pragma unroll
    for (int ct = 0; ct < 2; ct++)
      kf[ct] = *(const bf16x8*)(Kb + (base + kv0 + ct * 16 + lr) * 32 + lg * 8);
#pragma unroll
    for (int qt = 0; qt < 2; qt++) {
#pragma unroll
      for (int ct = 0; ct < 2; ct++) {
        f32x4 c = {};
        c = __builtin_amdgcn_mfma_f32_16x16x32_bf16(qf[qt], kf[ct], c, 0, 0, 0);
#pragma unroll
        for (int r = 0; r < 4; r++) {
          float p = __expf(c[r]);
          lpart[qt][r] += p;
          Pl[(qt * 16 + lg * 4 + r) * PSTR + ct * 16 + lr] = f2bf(p);
        }
      }
    }
#pragma unroll
    for (int qt = 0; qt < 2; qt++) {
      us4 plo = *(const us4*)&Pl[(qt * 16 + lr) * PSTR + lg * 8];
      us4 phi = *(const us4*)&Pl[(qt * 16 + lr) * PSTR + lg * 8 + 4];
      bf16x8 pf = {(short)plo[0], (short)plo[1], (short)plo[2], (short)plo[3],
                   (short)phi[0], (short)phi[1], (short)phi[2], (short)phi[3]};
#pragma unroll
      for (int dt = 0; dt < 2; dt++) {
        bf16x8 vf = *(const bf16x8*)(vb + ((size_t)(dt * 16 + lr) << 10) + kv0 + lg * 8);
        o[qt][dt] = __builtin_amdgcn_mfma_f32_16x16x32_bf16(pf, vf, o[qt][dt], 0, 0, 0);
      }
    }
  }
#pragma unroll
  for (int qt = 0; qt < 2; qt++) {
#pragma unroll
    for (int r = 0; r < 4; r++) {
      float l = lpart[qt][r];
      l += __shfl_xor(l, 1, 64); l += __shfl_xor(l, 2, 64);
      l += __shfl_xor(l, 4, 64); l += __shfl_xor(l, 8, 64);
      lpart[qt][r] = 1.f / l;
    }
  }
  const int b = bh >> 3, h = bh & 7;
#pragma unroll
  for (int qt = 0; qt < 2; qt++)
#pragma unroll
    for (int dt = 0; dt < 2; dt++)
#pragma unroll
      for (int r = 0; r < 4; r++) {
        int q = q0 + qt * 16 + lg * 4 + r;
        int c = h * 32 + dt * 16 + lr;
        obuf[((size_t)(b * NTOK + q)) * DIMC + c] = f2bf(o[qt][dt][r] * lpart[qt][r]);
      }
}

// ---------------- per-row LayerNorm + GELU, one row per wave, bf16 out -----------
__global__ void ln_gelu_k(const float* __restrict__ in, const float* __restrict__ g,
                          const float* __restrict__ bb, unsigned short* __restrict__ out) {
  int t = threadIdx.x;
  int lane = t & 63;
  int r = blockIdx.x * 4 + (t >> 6);
  const float* p = in + ((size_t)r << 8) + (lane << 2);
  float4 v = *(const float4*)p;
  float s1 = v.x + v.y + v.z + v.w;
  float s2 = v.x * v.x + v.y * v.y + v.z * v.z + v.w * v.w;
#pragma unroll
  for (int m = 1; m < 64; m <<= 1) {
    s1 += __shfl_xor(s1, m, 64);
    s2 += __shfl_xor(s2, m, 64);
  }
  float mu = s1 * (1.f / 256.f);
  float var = s2 * (1.f / 256.f) - mu * mu;
  float rstd = rsqrtf(var + 1e-5f);
  float4 gv = *(const float4*)(g + (lane << 2));
  float4 bv = *(const float4*)(bb + (lane << 2));
  us4 ob = {f2bf(gelu_f((v.x - mu) * rstd * gv.x + bv.x)),
            f2bf(gelu_f((v.y - mu) * rstd * gv.y + bv.y)),
            f2bf(gelu_f((v.z - mu) * rstd * gv.z + bv.z)),
            f2bf(gelu_f((v.w - mu) * rstd * gv.w + bv.w))};
  *(us4*)(out + ((size_t)r << 8) + (lane << 2)) = ob;
}

// ---- fused: LayerNorm + GELU + [B,HW,C]->NCHW transpose + identity add ----------
__global__ __launch_bounds__(256) void ln_trans_k(const float* __restrict__ in,
                                                  const float* __restrict__ g,
                                                  const float* __restrict__ bb,
                                                  const float* __restrict__ x,
                                                  float* __restrict__ out) {
  __shared__ float ys[32][257];
  const int b = blockIdx.y, s0 = blockIdx.x << 5;
  const int t = threadIdx.x, lane = t & 63, wv = t >> 6;
  float gv[4], bv[4];
#pragma unroll
  for (int e = 0; e < 4; e++) { gv[e] = g[lane + 64 * e]; bv[e] = bb[lane + 64 * e]; }
  for (int i = 0; i < 8; i++) {
    int tok = wv * 8 + i;
    size_t r = (size_t)(b * 1024 + s0 + tok) << 8;
    float v[4];
    float s1 = 0.f, s2 = 0.f;
#pragma unroll
    for (int e = 0; e < 4; e++) {
      v[e] = in[r + lane + 64 * e];
      s1 += v[e]; s2 += v[e] * v[e];
    }
#pragma unroll
    for (int m = 1; m < 64; m <<= 1) {
      s1 += __shfl_xor(s1, m, 64);
      s2 += __shfl_xor(s2, m, 64);
    }
    float mu = s1 * (1.f / 256.f);
    float var = s2 * (1.f / 256.f) - mu * mu;
    float rstd = rsqrtf(var + 1e-5f);
#pragma unroll
    for (int e = 0; e < 4; e++)
      ys[tok][lane + 64 * e] = gelu_f((v[e] - mu) * rstd * gv[e] + bv[e]);
  }
  __syncthreads();
  const int j = t & 31, cr = t >> 5;
  for (int c = cr; c < 256; c += 8) {
    size_t idx = ((size_t)(b * 256 + c) << 10) + s0 + j;
    out[idx] = x[idx] + ys[j][c];
  }
}

extern "C" void kernel_launch(void* const* d_in, const int* in_sizes, int n_in,
                              void* d_out, int out_size, void* d_ws, size_t ws_size,
                              hipStream_t stream) {
  const float* x     = (const float*)d_in[0];
  const float* dw_w  = (const float*)d_in[1];
  const float* dw_b  = (const float*)d_in[2];
  const float* qkv_w = (const float*)d_in[3];
  const float* c1_w  = (const float*)d_in[4];
  const float* c1_b  = (const float*)d_in[5];
  const float* ln1_g = (const float*)d_in[6];
  const float* ln1_b = (const float*)d_in[7];
  const float* c2_w  = (const float*)d_in[8];
  const float* c2_b  = (const float*)d_in[9];
  const float* ln2_g = (const float*)d_in[10];
  const float* ln2_b = (const float*)d_in[11];
  float* out = (float*)d_out;

  float* ws = (float*)d_ws;
  const size_t MF = (size_t)1 << 20;   // 1M floats = 4 MB
  // Lifetimes (peak 10 MF = 40 MB < 44 proven-safe):
  //   Wb [0,0.25M) lives to end | A0 [0.25M,1.25M) bf16, dead after mgemm_qkv
  //   Qb [2M,3M) Kb [3M,4M) Vt [4M,5M) bf16, dead after attn
  //   obuf bf16 [0.25M,1.25M) reuse A0 | buf1 [5M,7M) | m1 bf16 [7M,8M)
  //   buf2 [8M,10M)
  unsigned short* Wb = (unsigned short*)ws;
  unsigned short* A0 = (unsigned short*)(ws + MF / 4);
  unsigned short* Qb = (unsigned short*)(ws + 2 * MF);
  unsigned short* Kb = (unsigned short*)(ws + 3 * MF);
  unsigned short* Vtb = (unsigned short*)(ws + 4 * MF);
  unsigned short* obuf = (unsigned short*)(ws + MF / 4);
  float* buf1 = ws + 5 * MF;
  unsigned short* m1 = (unsigned short*)(ws + 7 * MF);
  float* buf2 = ws + 8 * MF;
  (void)in_sizes; (void)n_in; (void)out_size; (void)ws_size;

  dwt_k<<<2368, 256, 0, stream>>>(x, dw_w, dw_b, A0, qkv_w, c1_w, c2_w, Wb);
  mgemm_qkv_k<<<dim3(64, 12), 256, 0, stream>>>(A0, Wb, Qb, Kb, Vtb);
  attn_mfma_k<<<dim3(32, 64), 64, 0, stream>>>(Qb, Kb, Vtb, obuf);
  mgemm_k<true><<<dim3(4, 64), 256, 0, stream>>>(obuf, Wb + 196608, c1_b, buf1, 256);
  ln_gelu_k<<<2048, 256, 0, stream>>>(buf1, ln1_g, ln1_b, m1);
  mgemm_k<true><<<dim3(4, 64), 256, 0, stream>>>(m1, Wb + 262144, c2_b, buf2, 256);
  ln_trans_k<<<dim3(32, 8), 256, 0, stream>>>(buf2, ln2_g, ln2_b, x, out);
}